// Round 2
// baseline (410.740 us; speedup 1.0000x reference)
//
#include <hip/hip_runtime.h>
#include <hip/hip_bf16.h>

#define D      128
#define NHEAD  8
#define FE     5
#define LSEQ   4096
#define EPB    64          // edges per block in edge_kernel
#define NNODE  16384
#define EPS_LN 1e-5f
#define EPS_SM 1e-16f

typedef unsigned short ushort_t;
typedef __bf16 bf16x8 __attribute__((ext_vector_type(8)));
typedef float  f32x4  __attribute__((ext_vector_type(4)));

__device__ __forceinline__ ushort_t f2bf(float x) {
    __hip_bfloat16 b = __float2bfloat16(x);
    return __builtin_bit_cast(unsigned short, b);
}
__device__ __forceinline__ float bf2f(ushort_t u) {
    __hip_bfloat16 b = __builtin_bit_cast(__hip_bfloat16, u);
    return __bfloat162float(b);
}
__device__ __forceinline__ float i2f(int x)  { return __builtin_bit_cast(float, x); }
__device__ __forceinline__ int   f2i(float x){ return __builtin_bit_cast(int, x); }

union Pk8 { ushort_t u[8]; uint4 v; };

// ---------------------------------------------------------------------------
// pre_kernel:
//   blocks [0,47)    : swizzle weights into bf16 MFMA frag layouts
//     g <  10496 : B-frags for ek_w2, ev_w2, ea_w2, key_w, query_w, value_w
//     g >= 10496 : A-frags for layer-1 W1^T (3 MLPs), NATURAL neuron order
//       (neuron = mt*16 + mi; R12: the R11 baked permutation + direct
//        C->A bit_cast handoff was the only unpinned mapping and failed at
//        1e-2 absmax; redistribution now goes through wave-local LDS with
//        pinned D-write/A-read patterns instead).
//       K-space layout (hi/lo split + bias fold, f32-accurate layer-1):
//         kf[0,5)=W_hi (pairs ef_hi), kf[8,13)=W_hi (pairs ef_lo),
//         kf[16,21)=W_lo (pairs ef_hi), kf24/25=b1_hi/b1_lo (pair 1.0).
//   blocks [47,+1024): head histogram (cnt pre-zeroed by memset)
// ---------------------------------------------------------------------------
__global__ __launch_bounds__(256) void pre_kernel(
    const float* __restrict__ ekw2, const float* __restrict__ evw2,
    const float* __restrict__ eaw2,
    const float* __restrict__ kw, const float* __restrict__ qw,
    const float* __restrict__ vw,
    const float* __restrict__ eaw1, const float* __restrict__ eab1,
    const float* __restrict__ ekw1, const float* __restrict__ ekb1,
    const float* __restrict__ evw1, const float* __restrict__ evb1,
    ushort_t* __restrict__ eksw, ushort_t* __restrict__ evsw, ushort_t* __restrict__ easw,
    ushort_t* __restrict__ kwsw, ushort_t* __restrict__ qwsw, ushort_t* __restrict__ vwsw,
    ushort_t* __restrict__ w1fg,
    const int* __restrict__ bidx, const int* __restrict__ hidx,
    int* __restrict__ cnt, int E)
{
    const int t = threadIdx.x;
    if (blockIdx.x < 47) {
        const int g = blockIdx.x * 256 + t;
        if (g < 10496) {
            const float* src; ushort_t* dst; int frag, ncols = 128, nvalid = 128;
            if (g < 2048)       { src = ekw2; dst = eksw; frag = g; }
            else if (g < 4096)  { src = evw2; dst = evsw; frag = g - 2048; }
            else if (g < 4352)  { src = eaw2; dst = easw; frag = g - 4096; ncols = 8; nvalid = 8; }
            else if (g < 6400)  { src = kw;   dst = kwsw; frag = g - 4352; }
            else if (g < 8448)  { src = qw;   dst = qwsw; frag = g - 6400; }
            else                { src = vw;   dst = vwsw; frag = g - 8448; }
            const int s = (frag >> 6) & 3;
            const int l = frag & 63;
            const int n = ((frag >> 8) << 4) + (l & 15);
            Pk8 pk;
            #pragma unroll
            for (int j = 0; j < 8; ++j) {
                const int k = s * 32 + (l >> 4) * 8 + j;
                const float v = (n < nvalid) ? src[k * ncols + n] : 0.f;
                pk.u[j] = f2bf(v);
            }
            *(uint4*)(dst + (size_t)frag * 8) = pk.v;
            return;
        }
        // ---- layer-1 A-frags (W1^T, natural order, bias-folded, hi/lo) -----
        const int g2  = g - 10496;          // [0, 1536)
        const int mlp = g2 >> 9;            // 0:ea 1:ek 2:ev
        const int q   = g2 & 511;
        const int mt  = q >> 6;             // output-dim tile
        const int l   = q & 63;             // lane
        const int mi  = l & 15;             // within-tile output row (A row)
        const int gk  = l >> 4;             // k-group
        const float* w1 = (mlp == 0) ? eaw1 : (mlp == 1) ? ekw1 : evw1;
        const float* b1 = (mlp == 0) ? eab1 : (mlp == 1) ? ekb1 : evb1;
        const int neuron = mt * 16 + mi;    // NATURAL order (R12)
        Pk8 pk;
        #pragma unroll
        for (int j = 0; j < 8; ++j) {
            const int kf = gk * 8 + j;
            float v = 0.f; bool lo = false;
            if (kf < FE)                            v = w1[kf * D + neuron];
            else if (kf >= 8  && kf < 8  + FE)      v = w1[(kf - 8) * D + neuron];
            else if (kf >= 16 && kf < 16 + FE)    { v = w1[(kf - 16) * D + neuron]; lo = true; }
            else if (kf == 24)                      v = b1[neuron];
            else if (kf == 25)                    { v = b1[neuron]; lo = true; }
            const ushort_t hi = f2bf(v);
            pk.u[j] = lo ? f2bf(v - bf2f(hi)) : hi;
        }
        *(uint4*)(w1fg + (size_t)g2 * 8) = pk.v;
        return;
    }
    // ---------------- histogram ------------------------------------------
    const int e = (blockIdx.x - 47) * 256 + t;
    if (e < E) atomicAdd(&cnt[bidx[e] * LSEQ + hidx[e]], 1);
}

// ---------------------------------------------------------------------------
// Exclusive scan of the 16384-bin histogram (single block, ~5 µs).
// ---------------------------------------------------------------------------
__global__ __launch_bounds__(1024) void scan16k(
    const int* __restrict__ cnt, int* __restrict__ base)
{
    __shared__ int part[1024];
    const int t = threadIdx.x;
    int v[16], ex[16], s = 0;
    #pragma unroll
    for (int i = 0; i < 16; ++i) v[i] = cnt[t * 16 + i];
    #pragma unroll
    for (int i = 0; i < 16; ++i) { ex[i] = s; s += v[i]; }
    part[t] = s;
    __syncthreads();
    for (int off = 1; off < 1024; off <<= 1) {
        const int x = (t >= off) ? part[t - off] : 0;
        __syncthreads();
        part[t] += x;
        __syncthreads();
    }
    const int boff = (t > 0) ? part[t - 1] : 0;
    #pragma unroll
    for (int i = 0; i < 16; ++i) base[t * 16 + i] = boff + ex[i];
    if (t == 1023) base[NNODE] = boff + s;
}

// ---------------------------------------------------------------------------
// mid_kernel: two independent jobs overlapped in one dispatch:
//   blocks [0, 3*nqm)  : MFMA qkv GEMMs, 64 rows/block, bf16 out.
//   blocks [3*nqm, +)  : scatter_rec — sorted slot p per edge, packed 32 B
//                        record rec[p] = {ef[5], head, tail, pad}.
// ---------------------------------------------------------------------------
__global__ __launch_bounds__(256) void mid_kernel(
    const float* __restrict__ key, const float* __restrict__ value,
    const float* __restrict__ query,
    const float* __restrict__ key_b, const float* __restrict__ value_b,
    const float* __restrict__ query_b,
    const ushort_t* __restrict__ kwsw, const ushort_t* __restrict__ vwsw,
    const ushort_t* __restrict__ qwsw,
    ushort_t* __restrict__ k16, ushort_t* __restrict__ v16, ushort_t* __restrict__ q16,
    const int* __restrict__ bidx, const int* __restrict__ hidx, const int* __restrict__ tidx,
    const float* __restrict__ edge_feats,
    const int* __restrict__ base, int* __restrict__ cnt, float* __restrict__ rec,
    int nqm, int E)
{
    const int t  = threadIdx.x;
    const int nq = 3 * nqm;
    if ((int)blockIdx.x < nq) {
        const int which = blockIdx.x / nqm;
        const int blk   = blockIdx.x % nqm;
        const float* X     = (which == 0) ? key   : (which == 1) ? value   : query;
        const float* bias  = (which == 0) ? key_b : (which == 1) ? value_b : query_b;
        const ushort_t* Ww = (which == 0) ? kwsw  : (which == 1) ? vwsw    : qwsw;
        ushort_t* Y        = (which == 0) ? k16   : (which == 1) ? v16     : q16;

        const int mt    = t >> 6;
        const int l     = t & 63;
        const int rbase = blk * 64 + mt * 16;
        const int colb  = l & 15;
        const int row0  = (l >> 4) * 4;
        const int arow  = rbase + colb;        // A row for this lane (m = l&15)
        const int koff  = (l >> 4) * 8;        // k-offset within 32-chunk

        bf16x8 afr[4];
        #pragma unroll
        for (int s = 0; s < 4; ++s) {
            const float4 x0 = *(const float4*)&X[(size_t)arow * D + s * 32 + koff];
            const float4 x1 = *(const float4*)&X[(size_t)arow * D + s * 32 + koff + 4];
            Pk8 p8;
            p8.u[0] = f2bf(x0.x); p8.u[1] = f2bf(x0.y);
            p8.u[2] = f2bf(x0.z); p8.u[3] = f2bf(x0.w);
            p8.u[4] = f2bf(x1.x); p8.u[5] = f2bf(x1.y);
            p8.u[6] = f2bf(x1.z); p8.u[7] = f2bf(x1.w);
            afr[s] = __builtin_bit_cast(bf16x8, p8.v);
        }
        #pragma unroll
        for (int nt = 0; nt < 8; ++nt) {
            f32x4 acc = {0.f, 0.f, 0.f, 0.f};
            #pragma unroll
            for (int s = 0; s < 4; ++s) {
                const bf16x8 bfr = *(const bf16x8*)(Ww + (size_t)((nt * 4 + s) * 64 + l) * 8);
                acc = __builtin_amdgcn_mfma_f32_16x16x32_bf16(afr[s], bfr, acc, 0, 0, 0);
            }
            const int col = nt * 16 + colb;
            const float b = bias[col];
            #pragma unroll
            for (int r = 0; r < 4; ++r)
                Y[(size_t)(rbase + row0 + r) * D + col] = f2bf(acc[r] + b);
        }
        return;
    }

    // ---------------- scatter_rec ----------------------------------------
    const int e = (blockIdx.x - nq) * 256 + t;
    if (e >= E) return;
    const int bb = bidx[e];
    const int nh = bb * LSEQ + hidx[e];
    const int nt = bb * LSEQ + tidx[e];
    const int slot = atomicSub(&cnt[nh], 1) - 1;
    const int p = base[nh] + slot;
    float ef[FE];
    #pragma unroll
    for (int f = 0; f < FE; ++f) ef[f] = edge_feats[(size_t)e * FE + f];
    *(float4*)&rec[(size_t)p * 8]     = float4{ef[0], ef[1], ef[2], ef[3]};
    *(float4*)&rec[(size_t)p * 8 + 4] = float4{ef[4], i2f(nh), i2f(nt), 0.f};
}

// ---------------------------------------------------------------------------
// Fused edge kernel — barrier-free wave-local pipeline over SORTED positions.
// R12: layer-1 via MFMA (H^T = W1^T · X^T), frags read straight from global
// (24 KB, L1-resident). The MFMA C-tile (edge = lane&15, neurons in D-layout)
// is ReLU'd + LayerNorm'd in-register, then round-trips through a WAVE-LOCAL
// LDS tile hn[wave][edge][128+8] so layer-2 A-frags can be re-read with the
// standard (pinned) A-pattern. No baked permutation, no cross-wave sharing,
// still barrier-free after init. +8 ushort row pad kills write bank conflicts.
// __launch_bounds__(256,4): the ONLY no-spill config (R9/R10: don't raise).
// ---------------------------------------------------------------------------
__global__ __launch_bounds__(256, 4) void edge_kernel(
    const float* __restrict__ rec,
    const ushort_t* __restrict__ w1fg,
    const float* __restrict__ ea_g,  const float* __restrict__ ea_be, const float* __restrict__ ea_b2,
    const float* __restrict__ ek_g,  const float* __restrict__ ek_be, const float* __restrict__ ek_b2,
    const float* __restrict__ ev_g,  const float* __restrict__ ev_be, const float* __restrict__ ev_b2,
    const ushort_t* __restrict__ easw, const ushort_t* __restrict__ eksw, const ushort_t* __restrict__ evsw,
    const ushort_t* __restrict__ k16, const ushort_t* __restrict__ q16, const ushort_t* __restrict__ v16,
    float* __restrict__ ex_ws, ushort_t* __restrict__ vs_ws)
{
    __shared__ ushort_t hn[4][16][136];     // 17 KB wave-local h_n round-trip
    __shared__ float pg[3][D], pbe[3][D];
    __shared__ float pb2k[D], pb2v[D], pb2a[NHEAD];
    __shared__ float ef_s[EPB][FE];
    __shared__ int   eh_s[EPB], et_s[EPB];

    const int t   = threadIdx.x;
    const int e0g = blockIdx.x * EPB;   // sorted-position base

    if (t < D) {
        pg [0][t] = ea_g [t]; pg [1][t] = ek_g [t]; pg [2][t] = ev_g [t];
        pbe[0][t] = ea_be[t]; pbe[1][t] = ek_be[t]; pbe[2][t] = ev_be[t];
        pb2k[t] = ek_b2[t];   pb2v[t] = ev_b2[t];
        if (t < NHEAD) pb2a[t] = ea_b2[t];
    }
    if (t < 128) {
        const int pl = t >> 1, half = t & 1;
        const float4 v = *(const float4*)&rec[((size_t)e0g + pl) * 8 + half * 4];
        if (half == 0) {
            ef_s[pl][0] = v.x; ef_s[pl][1] = v.y; ef_s[pl][2] = v.z; ef_s[pl][3] = v.w;
        } else {
            ef_s[pl][4] = v.x; eh_s[pl] = f2i(v.y); et_s[pl] = f2i(v.z);
        }
    }
    __syncthreads();     // the only barrier

    const int mt   = t >> 6;        // wave id == m-tile (16 edges per wave)
    const int l    = t & 63;        // lane
    const int h4   = l >> 4;        // k-group / h-group
    const int row0 = h4 * 4;        // consumer: accumulator row base
    const int colb = l & 15;        // consumer: column within n-tile
    const int bsrc = (l & 48);      // row-group base for ea broadcasts

    int tn[4], hnn[4];
    #pragma unroll
    for (int r = 0; r < 4; ++r) { tn[r] = et_s[mt*16 + row0 + r]; hnn[r] = eh_s[mt*16 + row0 + r]; }

    // ---- shared layer-1 B operand: X^T frag (edge = l&15), hi/lo + bias ----
    bf16x8 xfr;
    {
        const float* e = ef_s[mt * 16 + colb];
        Pk8 xf;
        if (h4 == 3) {
            const ushort_t one = f2bf(1.f);
            xf.u[0] = one; xf.u[1] = one;
            #pragma unroll
            for (int j = 2; j < 8; ++j) xf.u[j] = 0;
        } else {
            #pragma unroll
            for (int f = 0; f < FE; ++f) {
                const float v = e[f];
                const ushort_t hi = f2bf(v);
                xf.u[f] = (h4 == 1) ? f2bf(v - bf2f(hi)) : hi;
            }
            xf.u[5] = 0; xf.u[6] = 0; xf.u[7] = 0;
        }
        xfr = __builtin_bit_cast(bf16x8, xf.v);
    }

    ushort_t* hnrow = &hn[mt][colb][0];     // this lane's edge row (wave-local)

    // layer-1 via MFMA; h_n lands back in afr[] via the LDS round-trip.
    auto first_layer = [&](int m, bf16x8 afr[4]) {
        const f32x4 zero = {0.f, 0.f, 0.f, 0.f};
        f32x4 acc[8];
        #pragma unroll
        for (int mtile = 0; mtile < 8; ++mtile) {
            const bf16x8 aw = *(const bf16x8*)(w1fg + (size_t)((m * 8 + mtile) * 64 + l) * 8);
            acc[mtile] = __builtin_amdgcn_mfma_f32_16x16x32_bf16(aw, xfr, zero, 0, 0, 0);
        }
        float s1 = 0.f, s2 = 0.f;
        #pragma unroll
        for (int mtile = 0; mtile < 8; ++mtile) {
            #pragma unroll
            for (int r = 0; r < 4; ++r) {
                const float v = fmaxf(acc[mtile][r], 0.f);
                acc[mtile][r] = v;
                s1 += v; s2 += v * v;
            }
        }
        s1 += __shfl_xor(s1, 16); s1 += __shfl_xor(s1, 32);
        s2 += __shfl_xor(s2, 16); s2 += __shfl_xor(s2, 32);
        const float mu = s1 * (1.f / 128.f);
        const float rs = rsqrtf(s2 * (1.f / 128.f) - mu * mu + EPS_LN);
        // D-layout write: lane holds rows 4*h4+r of m-tile mtile for its edge;
        // natural neuron = mtile*16 + 4*h4 + r.
        #pragma unroll
        for (int mtile = 0; mtile < 8; ++mtile) {
            const int n0 = mtile * 16 + 4 * h4;
            const float4 g4 = *(const float4*)&pg[m][n0];
            const float4 b4 = *(const float4*)&pbe[m][n0];
            uint2 w;
            w.x = (unsigned)f2bf(fmaf((acc[mtile][0] - mu) * rs, g4.x, b4.x))
                | ((unsigned)f2bf(fmaf((acc[mtile][1] - mu) * rs, g4.y, b4.y)) << 16);
            w.y = (unsigned)f2bf(fmaf((acc[mtile][2] - mu) * rs, g4.z, b4.z))
                | ((unsigned)f2bf(fmaf((acc[mtile][3] - mu) * rs, g4.w, b4.w)) << 16);
            *(uint2*)&hnrow[n0] = w;
        }
        // pinned A-pattern read: elem j of frag s = h_n[edge l&15][32s+8h4+j]
        #pragma unroll
        for (int s = 0; s < 4; ++s)
            afr[s] = *(const bf16x8*)&hnrow[32 * s + 8 * h4];
    };

    bf16x8 afr[4];

    // ================= MLP 0: ea (attention bias, cols padded 8->16) ========
    float eaacc[4];
    first_layer(0, afr);
    {
        f32x4 acc = {0.f, 0.f, 0.f, 0.f};
        #pragma unroll
        for (int s = 0; s < 4; ++s) {
            const bf16x8 bfr = *(const bf16x8*)(easw + (size_t)(s * 64 + l) * 8);
            acc = __builtin_amdgcn_mfma_f32_16x16x32_bf16(afr[s], bfr, acc, 0, 0, 0);
        }
        #pragma unroll
        for (int r = 0; r < 4; ++r) eaacc[r] = acc[r];   // raw; bias added later
    }

    // ================= MLP 1: ek -> scores -> exp -> ex_ws ==================
    first_layer(1, afr);
    #pragma unroll
    for (int nt = 0; nt < NHEAD; ++nt) {
        f32x4 acc = {0.f, 0.f, 0.f, 0.f};
        #pragma unroll
        for (int s = 0; s < 4; ++s) {
            const bf16x8 bfr = *(const bf16x8*)(eksw + (size_t)((nt * 4 + s) * 64 + l) * 8);
            acc = __builtin_amdgcn_mfma_f32_16x16x32_bf16(afr[s], bfr, acc, 0, 0, 0);
        }
        const int col = nt * 16 + colb;
        const float b2 = pb2k[col];
        const float ba = pb2a[nt];
        float pr[4];
        #pragma unroll
        for (int r = 0; r < 4; ++r)
            pr[r] = (acc[r] + b2 + bf2f(k16[(size_t)tn[r] * D + col]))
                    * bf2f(q16[(size_t)hnn[r] * D + col]);
        #pragma unroll
        for (int m = 1; m < 16; m <<= 1) {
            #pragma unroll
            for (int r = 0; r < 4; ++r) pr[r] += __shfl_xor(pr[r], m);
        }
        #pragma unroll
        for (int r = 0; r < 4; ++r) {
            // segment-max skipped: |score| small, exp cannot overflow.
            const float ea = __shfl(eaacc[r], bsrc | nt);
            const float ex = __expf(pr[r] + ea + ba);
            if (colb == nt)
                ex_ws[(size_t)(e0g + mt*16 + row0 + r) * NHEAD + nt] = ex;
        }
    }

    // ================= MLP 2: ev -> raw vs (bf16) ===========================
    first_layer(2, afr);
    #pragma unroll
    for (int nt = 0; nt < NHEAD; ++nt) {
        f32x4 acc = {0.f, 0.f, 0.f, 0.f};
        #pragma unroll
        for (int s = 0; s < 4; ++s) {
            const bf16x8 bfr = *(const bf16x8*)(evsw + (size_t)((nt * 4 + s) * 64 + l) * 8);
            acc = __builtin_amdgcn_mfma_f32_16x16x32_bf16(afr[s], bfr, acc, 0, 0, 0);
        }
        const int col = nt * 16 + colb;
        const float b2 = pb2v[col];
        #pragma unroll
        for (int r = 0; r < 4; ++r) {
            const float vs = acc[r] + b2 + bf2f(v16[(size_t)tn[r] * D + col]);
            vs_ws[(size_t)(e0g + mt*16 + row0 + r) * D + col] = f2bf(vs);
        }
    }
}

// ---------------------------------------------------------------------------
// agg_out: 512 threads, 16 nodes per block, 4 row-groups (4 nodes each).
// Phase 1: stream each node's contiguous sorted segment of (ex, vs) -> LDS y.
// Phase 2: project y @ W + b (each row-group does 4 output rows).
// Plain bounds: no waves/EU contract (R9/R10: never squeeze the allocator).
// ---------------------------------------------------------------------------
__global__ __launch_bounds__(512) void agg_out(
    const int* __restrict__ base,
    const float* __restrict__ ex_ws, const ushort_t* __restrict__ vs_ws,
    const float* __restrict__ W, const float* __restrict__ bias,
    float* __restrict__ out)
{
    __shared__ float xs[D][20];
    const int t  = threadIdx.x;
    const int rg = t >> 7;          // 0..3: node/row group
    const int j  = t & 127;
    const int h  = j >> 4;
    const int n0 = blockIdx.x * 16;

    // ---- phase 1: per-node segmented reduction (contiguous, no indices) ----
    #pragma unroll
    for (int ni = 0; ni < 4; ++ni) {
        const int n  = n0 + rg * 4 + ni;
        const int s0 = base[n], s1 = base[n + 1];
        float acc = 0.f, den = 0.f;
        int p = s0;
        for (; p + 4 <= s1; p += 4) {
            float ex4[4], vs4[4];
            #pragma unroll
            for (int r = 0; r < 4; ++r) {
                ex4[r] = ex_ws[(size_t)(p + r) * NHEAD + h];
                vs4[r] = bf2f(vs_ws[(size_t)(p + r) * D + j]);
            }
            #pragma unroll
            for (int r = 0; r < 4; ++r) {
                den += ex4[r];
                acc = fmaf(ex4[r], vs4[r], acc);
            }
        }
        for (; p < s1; ++p) {
            const float ex = ex_ws[(size_t)p * NHEAD + h];
            den += ex;
            acc = fmaf(ex, bf2f(vs_ws[(size_t)p * D + j]), acc);
        }
        xs[j][rg * 4 + ni] = acc / (den + EPS_SM);
    }
    __syncthreads();

    // ---- phase 2: out projection; row-group rg does rows rg*4..rg*4+4 ------
    float acc[4];
    const float b = bias[j];
    #pragma unroll
    for (int r = 0; r < 4; ++r) acc[r] = b;
    #pragma unroll 4
    for (int i = 0; i < D; ++i) {
        const float w = W[i * D + j];
        const float4 y4 = *(const float4*)&xs[i][rg * 4];
        acc[0] = fmaf(y4.x, w, acc[0]); acc[1] = fmaf(y4.y, w, acc[1]);
        acc[2] = fmaf(y4.z, w, acc[2]); acc[3] = fmaf(y4.w, w, acc[3]);
    }
    #pragma unroll
    for (int r = 0; r < 4; ++r)
        out[(size_t)(n0 + rg * 4 + r) * D + j] = acc[r];
}

// ---------------------------------------------------------------------------
extern "C" void kernel_launch(void* const* d_in, const int* in_sizes, int n_in,
                              void* d_out, int out_size, void* d_ws, size_t ws_size,
                              hipStream_t stream)
{
    const float* key        = (const float*)d_in[0];
    const float* value      = (const float*)d_in[1];
    const float* query      = (const float*)d_in[2];
    const float* edge_feats = (const float*)d_in[3];
    const int*   bidx       = (const int*)d_in[5];
    const int*   hidx       = (const int*)d_in[6];
    const int*   tidx       = (const int*)d_in[7];
    const float* key_w   = (const float*)d_in[8];  const float* key_b   = (const float*)d_in[9];
    const float* query_w = (const float*)d_in[10]; const float* query_b = (const float*)d_in[11];
    const float* value_w = (const float*)d_in[12]; const float* value_b = (const float*)d_in[13];
    const float* proj_w  = (const float*)d_in[14]; const float* proj_b  = (const float*)d_in[15];

    const int N = in_sizes[0] / D;   // 16384 nodes
    const int E = in_sizes[5];       // 262144 edges

    char* ws = (char*)d_ws;
    ushort_t* k16   = (ushort_t*)ws; ws += (size_t)N * D * 2;
    ushort_t* q16   = (ushort_t*)ws; ws += (size_t)N * D * 2;
    ushort_t* v16   = (ushort_t*)ws; ws += (size_t)N * D * 2;
    float* ex_ws    = (float*)ws;    ws += (size_t)E * NHEAD * 4;
    ushort_t* vs_ws = (ushort_t*)ws; ws += (size_t)E * D * 2;
    float* rec      = (float*)ws;    ws += (size_t)E * 8 * 4;
    ushort_t* eksw  = (ushort_t*)ws; ws += (size_t)2048 * 8 * 2;
    ushort_t* evsw  = (ushort_t*)ws; ws += (size_t)2048 * 8 * 2;
    ushort_t* easw  = (ushort_t*)ws; ws += (size_t)256 * 8 * 2;
    ushort_t* kwsw  = (ushort_t*)ws; ws += (size_t)2048 * 8 * 2;
    ushort_t* qwsw  = (ushort_t*)ws; ws += (size_t)2048 * 8 * 2;
    ushort_t* vwsw  = (ushort_t*)ws; ws += (size_t)2048 * 8 * 2;
    ushort_t* w1fg  = (ushort_t*)ws; ws += (size_t)1536 * 8 * 2;
    int* base = (int*)ws;  ws += (size_t)(N + 1) * 4;
    int* cnt  = (int*)ws;  ws += (size_t)N * 4;

    const int nqm   = N / 64;             // MFMA-qkv blocks per matrix (256)
    const int nhist = (E + 255) / 256;    // 1024

    hipMemsetAsync(cnt, 0, (size_t)N * 4, stream);

    pre_kernel<<<47 + nhist, 256, 0, stream>>>(
        (const float*)d_in[26], (const float*)d_in[32], (const float*)d_in[20],
        key_w, query_w, value_w,
        (const float*)d_in[16], (const float*)d_in[17],
        (const float*)d_in[22], (const float*)d_in[23],
        (const float*)d_in[28], (const float*)d_in[29],
        eksw, evsw, easw, kwsw, qwsw, vwsw, w1fg,
        bidx, hidx, cnt, E);

    scan16k<<<1, 1024, 0, stream>>>(cnt, base);

    mid_kernel<<<3 * nqm + nhist, 256, 0, stream>>>(
        key, value, query,
        key_b, value_b, query_b,
        kwsw, vwsw, qwsw,
        k16, v16, q16,
        bidx, hidx, tidx, edge_feats,
        base, cnt, rec, nqm, E);

    edge_kernel<<<E / EPB, 256, 0, stream>>>(
        rec, w1fg,
        (const float*)d_in[18], (const float*)d_in[19], (const float*)d_in[21],
        (const float*)d_in[24], (const float*)d_in[25], (const float*)d_in[27],
        (const float*)d_in[30], (const float*)d_in[31], (const float*)d_in[33],
        easw, eksw, evsw,
        k16, q16, v16,
        ex_ws, vs_ws);

    agg_out<<<N / 16, 512, 0, stream>>>(base, ex_ws, vs_ws, proj_w, proj_b, (float*)d_out);
}

// Round 3
// 367.152 us; speedup vs baseline: 1.1187x; 1.1187x over previous
//
#include <hip/hip_runtime.h>
#include <hip/hip_bf16.h>

#define D      128
#define NHEAD  8
#define FE     5
#define LSEQ   4096
#define EPB    64          // edges per block in edge_kernel
#define NNODE  16384
#define EPS_LN 1e-5f
#define EPS_SM 1e-16f

typedef unsigned short ushort_t;
typedef __bf16 bf16x8 __attribute__((ext_vector_type(8)));
typedef float  f32x4  __attribute__((ext_vector_type(4)));

__device__ __forceinline__ ushort_t f2bf(float x) {
    __hip_bfloat16 b = __float2bfloat16(x);
    return __builtin_bit_cast(unsigned short, b);
}
__device__ __forceinline__ float bf2f(ushort_t u) {
    __hip_bfloat16 b = __builtin_bit_cast(__hip_bfloat16, u);
    return __bfloat162float(b);
}
__device__ __forceinline__ float i2f(int x)  { return __builtin_bit_cast(float, x); }
__device__ __forceinline__ int   f2i(float x){ return __builtin_bit_cast(int, x); }

union Pk8 { ushort_t u[8]; uint4 v; };

// ---------------------------------------------------------------------------
// pre_kernel:
//   blocks [0,47)    : swizzle weights into bf16 MFMA frag layouts
//     g <  10496 : B-frags for ek_w2, ev_w2, ea_w2, key_w, query_w, value_w
//     g >= 10496 : A-frags for layer-1 W1^T (3 MLPs), NATURAL neuron order
//       (neuron = mt*16 + mi). K-space layout (hi/lo split + bias fold,
//       f32-accurate layer-1):
//         kf[0,5)=W_hi (pairs ef_hi), kf[8,13)=W_hi (pairs ef_lo),
//         kf[16,21)=W_lo (pairs ef_hi), kf24/25=b1_hi/b1_lo (pair 1.0).
//   blocks [47,+1024): head histogram (cnt pre-zeroed by memset)
// ---------------------------------------------------------------------------
__global__ __launch_bounds__(256) void pre_kernel(
    const float* __restrict__ ekw2, const float* __restrict__ evw2,
    const float* __restrict__ eaw2,
    const float* __restrict__ kw, const float* __restrict__ qw,
    const float* __restrict__ vw,
    const float* __restrict__ eaw1, const float* __restrict__ eab1,
    const float* __restrict__ ekw1, const float* __restrict__ ekb1,
    const float* __restrict__ evw1, const float* __restrict__ evb1,
    ushort_t* __restrict__ eksw, ushort_t* __restrict__ evsw, ushort_t* __restrict__ easw,
    ushort_t* __restrict__ kwsw, ushort_t* __restrict__ qwsw, ushort_t* __restrict__ vwsw,
    ushort_t* __restrict__ w1fg,
    const int* __restrict__ bidx, const int* __restrict__ hidx,
    int* __restrict__ cnt, int E)
{
    const int t = threadIdx.x;
    if (blockIdx.x < 47) {
        const int g = blockIdx.x * 256 + t;
        if (g < 10496) {
            const float* src; ushort_t* dst; int frag, ncols = 128, nvalid = 128;
            if (g < 2048)       { src = ekw2; dst = eksw; frag = g; }
            else if (g < 4096)  { src = evw2; dst = evsw; frag = g - 2048; }
            else if (g < 4352)  { src = eaw2; dst = easw; frag = g - 4096; ncols = 8; nvalid = 8; }
            else if (g < 6400)  { src = kw;   dst = kwsw; frag = g - 4352; }
            else if (g < 8448)  { src = qw;   dst = qwsw; frag = g - 6400; }
            else                { src = vw;   dst = vwsw; frag = g - 8448; }
            const int s = (frag >> 6) & 3;
            const int l = frag & 63;
            const int n = ((frag >> 8) << 4) + (l & 15);
            Pk8 pk;
            #pragma unroll
            for (int j = 0; j < 8; ++j) {
                const int k = s * 32 + (l >> 4) * 8 + j;
                const float v = (n < nvalid) ? src[k * ncols + n] : 0.f;
                pk.u[j] = f2bf(v);
            }
            *(uint4*)(dst + (size_t)frag * 8) = pk.v;
            return;
        }
        // ---- layer-1 A-frags (W1^T, natural order, bias-folded, hi/lo) -----
        const int g2  = g - 10496;          // [0, 1536)
        const int mlp = g2 >> 9;            // 0:ea 1:ek 2:ev
        const int q   = g2 & 511;
        const int mt  = q >> 6;             // output-dim tile
        const int l   = q & 63;             // lane
        const int mi  = l & 15;             // within-tile output row (A row)
        const int gk  = l >> 4;             // k-group
        const float* w1 = (mlp == 0) ? eaw1 : (mlp == 1) ? ekw1 : evw1;
        const float* b1 = (mlp == 0) ? eab1 : (mlp == 1) ? ekb1 : evb1;
        const int neuron = mt * 16 + mi;    // NATURAL order
        Pk8 pk;
        #pragma unroll
        for (int j = 0; j < 8; ++j) {
            const int kf = gk * 8 + j;
            float v = 0.f; bool lo = false;
            if (kf < FE)                            v = w1[kf * D + neuron];
            else if (kf >= 8  && kf < 8  + FE)      v = w1[(kf - 8) * D + neuron];
            else if (kf >= 16 && kf < 16 + FE)    { v = w1[(kf - 16) * D + neuron]; lo = true; }
            else if (kf == 24)                      v = b1[neuron];
            else if (kf == 25)                    { v = b1[neuron]; lo = true; }
            const ushort_t hi = f2bf(v);
            pk.u[j] = lo ? f2bf(v - bf2f(hi)) : hi;
        }
        *(uint4*)(w1fg + (size_t)g2 * 8) = pk.v;
        return;
    }
    // ---------------- histogram ------------------------------------------
    const int e = (blockIdx.x - 47) * 256 + t;
    if (e < E) atomicAdd(&cnt[bidx[e] * LSEQ + hidx[e]], 1);
}

// ---------------------------------------------------------------------------
// Exclusive scan of the 16384-bin histogram (single block, ~5 µs).
// ---------------------------------------------------------------------------
__global__ __launch_bounds__(1024) void scan16k(
    const int* __restrict__ cnt, int* __restrict__ base)
{
    __shared__ int part[1024];
    const int t = threadIdx.x;
    int v[16], ex[16], s = 0;
    #pragma unroll
    for (int i = 0; i < 16; ++i) v[i] = cnt[t * 16 + i];
    #pragma unroll
    for (int i = 0; i < 16; ++i) { ex[i] = s; s += v[i]; }
    part[t] = s;
    __syncthreads();
    for (int off = 1; off < 1024; off <<= 1) {
        const int x = (t >= off) ? part[t - off] : 0;
        __syncthreads();
        part[t] += x;
        __syncthreads();
    }
    const int boff = (t > 0) ? part[t - 1] : 0;
    #pragma unroll
    for (int i = 0; i < 16; ++i) base[t * 16 + i] = boff + ex[i];
    if (t == 1023) base[NNODE] = boff + s;
}

// ---------------------------------------------------------------------------
// mid_kernel: two independent jobs overlapped in one dispatch:
//   blocks [0, 3*nqm)  : MFMA qkv GEMMs, 64 rows/block, bf16 out.
//   blocks [3*nqm, +)  : scatter_rec — sorted slot p per edge, packed 32 B
//                        record rec[p] = {ef[5], head, tail, pad}.
// ---------------------------------------------------------------------------
__global__ __launch_bounds__(256) void mid_kernel(
    const float* __restrict__ key, const float* __restrict__ value,
    const float* __restrict__ query,
    const float* __restrict__ key_b, const float* __restrict__ value_b,
    const float* __restrict__ query_b,
    const ushort_t* __restrict__ kwsw, const ushort_t* __restrict__ vwsw,
    const ushort_t* __restrict__ qwsw,
    ushort_t* __restrict__ k16, ushort_t* __restrict__ v16, ushort_t* __restrict__ q16,
    const int* __restrict__ bidx, const int* __restrict__ hidx, const int* __restrict__ tidx,
    const float* __restrict__ edge_feats,
    const int* __restrict__ base, int* __restrict__ cnt, float* __restrict__ rec,
    int nqm, int E)
{
    const int t  = threadIdx.x;
    const int nq = 3 * nqm;
    if ((int)blockIdx.x < nq) {
        const int which = blockIdx.x / nqm;
        const int blk   = blockIdx.x % nqm;
        const float* X     = (which == 0) ? key   : (which == 1) ? value   : query;
        const float* bias  = (which == 0) ? key_b : (which == 1) ? value_b : query_b;
        const ushort_t* Ww = (which == 0) ? kwsw  : (which == 1) ? vwsw    : qwsw;
        ushort_t* Y        = (which == 0) ? k16   : (which == 1) ? v16     : q16;

        const int mt    = t >> 6;
        const int l     = t & 63;
        const int rbase = blk * 64 + mt * 16;
        const int colb  = l & 15;
        const int row0  = (l >> 4) * 4;
        const int arow  = rbase + colb;        // A row for this lane (m = l&15)
        const int koff  = (l >> 4) * 8;        // k-offset within 32-chunk

        bf16x8 afr[4];
        #pragma unroll
        for (int s = 0; s < 4; ++s) {
            const float4 x0 = *(const float4*)&X[(size_t)arow * D + s * 32 + koff];
            const float4 x1 = *(const float4*)&X[(size_t)arow * D + s * 32 + koff + 4];
            Pk8 p8;
            p8.u[0] = f2bf(x0.x); p8.u[1] = f2bf(x0.y);
            p8.u[2] = f2bf(x0.z); p8.u[3] = f2bf(x0.w);
            p8.u[4] = f2bf(x1.x); p8.u[5] = f2bf(x1.y);
            p8.u[6] = f2bf(x1.z); p8.u[7] = f2bf(x1.w);
            afr[s] = __builtin_bit_cast(bf16x8, p8.v);
        }
        #pragma unroll
        for (int nt = 0; nt < 8; ++nt) {
            f32x4 acc = {0.f, 0.f, 0.f, 0.f};
            #pragma unroll
            for (int s = 0; s < 4; ++s) {
                const bf16x8 bfr = *(const bf16x8*)(Ww + (size_t)((nt * 4 + s) * 64 + l) * 8);
                acc = __builtin_amdgcn_mfma_f32_16x16x32_bf16(afr[s], bfr, acc, 0, 0, 0);
            }
            const int col = nt * 16 + colb;
            const float b = bias[col];
            #pragma unroll
            for (int r = 0; r < 4; ++r)
                Y[(size_t)(rbase + row0 + r) * D + col] = f2bf(acc[r] + b);
        }
        return;
    }

    // ---------------- scatter_rec ----------------------------------------
    const int e = (blockIdx.x - nq) * 256 + t;
    if (e >= E) return;
    const int bb = bidx[e];
    const int nh = bb * LSEQ + hidx[e];
    const int nt = bb * LSEQ + tidx[e];
    const int slot = atomicSub(&cnt[nh], 1) - 1;
    const int p = base[nh] + slot;
    float ef[FE];
    #pragma unroll
    for (int f = 0; f < FE; ++f) ef[f] = edge_feats[(size_t)e * FE + f];
    *(float4*)&rec[(size_t)p * 8]     = float4{ef[0], ef[1], ef[2], ef[3]};
    *(float4*)&rec[(size_t)p * 8 + 4] = float4{ef[4], i2f(nh), i2f(nt), 0.f};
}

// ---------------------------------------------------------------------------
// Fused edge kernel — barrier-free wave-local pipeline over SORTED positions.
// R13: layer-1 MFMA is TWO-PASS (recompute): pass 1 runs the 8 MFMAs only to
// accumulate LN statistics (acc transient, 4 regs); pass 2 recomputes each
// tile, normalizes, and stores straight to the wave-local LDS tile. This
// kills the f32x4 acc[8] 32-register live range that blew the (256,4) cap
// of 128 unified VGPR+AGPR in R12 and caused ~500 B/thread scratch spill
// (WRITE_SIZE 82->421 MB). Extra 24 MFMA/wave cost ~0.8 us at 4.7% MfmaUtil.
// Numerics identical to R12 (passed at 4.88e-4).
// __launch_bounds__(256,4): the ONLY no-spill config (R9/R10: don't raise).
// ---------------------------------------------------------------------------
__global__ __launch_bounds__(256, 4) void edge_kernel(
    const float* __restrict__ rec,
    const ushort_t* __restrict__ w1fg,
    const float* __restrict__ ea_g,  const float* __restrict__ ea_be, const float* __restrict__ ea_b2,
    const float* __restrict__ ek_g,  const float* __restrict__ ek_be, const float* __restrict__ ek_b2,
    const float* __restrict__ ev_g,  const float* __restrict__ ev_be, const float* __restrict__ ev_b2,
    const ushort_t* __restrict__ easw, const ushort_t* __restrict__ eksw, const ushort_t* __restrict__ evsw,
    const ushort_t* __restrict__ k16, const ushort_t* __restrict__ q16, const ushort_t* __restrict__ v16,
    float* __restrict__ ex_ws, ushort_t* __restrict__ vs_ws)
{
    __shared__ ushort_t hn[4][16][136];     // 17 KB wave-local h_n round-trip
    __shared__ float pg[3][D], pbe[3][D];
    __shared__ float pb2k[D], pb2v[D], pb2a[NHEAD];
    __shared__ float ef_s[EPB][FE];
    __shared__ int   eh_s[EPB], et_s[EPB];

    const int t   = threadIdx.x;
    const int e0g = blockIdx.x * EPB;   // sorted-position base

    if (t < D) {
        pg [0][t] = ea_g [t]; pg [1][t] = ek_g [t]; pg [2][t] = ev_g [t];
        pbe[0][t] = ea_be[t]; pbe[1][t] = ek_be[t]; pbe[2][t] = ev_be[t];
        pb2k[t] = ek_b2[t];   pb2v[t] = ev_b2[t];
        if (t < NHEAD) pb2a[t] = ea_b2[t];
    }
    if (t < 128) {
        const int pl = t >> 1, half = t & 1;
        const float4 v = *(const float4*)&rec[((size_t)e0g + pl) * 8 + half * 4];
        if (half == 0) {
            ef_s[pl][0] = v.x; ef_s[pl][1] = v.y; ef_s[pl][2] = v.z; ef_s[pl][3] = v.w;
        } else {
            ef_s[pl][4] = v.x; eh_s[pl] = f2i(v.y); et_s[pl] = f2i(v.z);
        }
    }
    __syncthreads();     // the only barrier

    const int mt   = t >> 6;        // wave id == m-tile (16 edges per wave)
    const int l    = t & 63;        // lane
    const int h4   = l >> 4;        // k-group / h-group
    const int row0 = h4 * 4;        // consumer: accumulator row base
    const int colb = l & 15;        // consumer: column within n-tile
    const int bsrc = (l & 48);      // row-group base for ea broadcasts

    // ---- shared layer-1 B operand: X^T frag (edge = l&15), hi/lo + bias ----
    bf16x8 xfr;
    {
        const float* e = ef_s[mt * 16 + colb];
        Pk8 xf;
        if (h4 == 3) {
            const ushort_t one = f2bf(1.f);
            xf.u[0] = one; xf.u[1] = one;
            #pragma unroll
            for (int j = 2; j < 8; ++j) xf.u[j] = 0;
        } else {
            #pragma unroll
            for (int f = 0; f < FE; ++f) {
                const float v = e[f];
                const ushort_t hi = f2bf(v);
                xf.u[f] = (h4 == 1) ? f2bf(v - bf2f(hi)) : hi;
            }
            xf.u[5] = 0; xf.u[6] = 0; xf.u[7] = 0;
        }
        xfr = __builtin_bit_cast(bf16x8, xf.v);
    }

    ushort_t* hnrow = &hn[mt][colb][0];     // this lane's edge row (wave-local)

    // layer-1 via two-pass MFMA; h_n lands in afr[] via the LDS round-trip.
    auto first_layer = [&](int m, bf16x8 afr[4]) {
        const f32x4 zero = {0.f, 0.f, 0.f, 0.f};
        float s1 = 0.f, s2 = 0.f;
        // pass 1: LN statistics only; acc dies each iteration.
        #pragma unroll
        for (int mtile = 0; mtile < 8; ++mtile) {
            const bf16x8 aw = *(const bf16x8*)(w1fg + (size_t)((m * 8 + mtile) * 64 + l) * 8);
            const f32x4 acc = __builtin_amdgcn_mfma_f32_16x16x32_bf16(aw, xfr, zero, 0, 0, 0);
            #pragma unroll
            for (int r = 0; r < 4; ++r) {
                const float v = fmaxf(acc[r], 0.f);
                s1 += v; s2 += v * v;
            }
        }
        s1 += __shfl_xor(s1, 16); s1 += __shfl_xor(s1, 32);
        s2 += __shfl_xor(s2, 16); s2 += __shfl_xor(s2, 32);
        const float mu = s1 * (1.f / 128.f);
        const float rs = rsqrtf(s2 * (1.f / 128.f) - mu * mu + EPS_LN);
        // pass 2: recompute, normalize, store to wave-local LDS (D-layout:
        // lane holds rows 4*h4+r of m-tile mtile for edge colb; natural
        // neuron = mtile*16 + 4*h4 + r).
        #pragma unroll
        for (int mtile = 0; mtile < 8; ++mtile) {
            const bf16x8 aw = *(const bf16x8*)(w1fg + (size_t)((m * 8 + mtile) * 64 + l) * 8);
            const f32x4 acc = __builtin_amdgcn_mfma_f32_16x16x32_bf16(aw, xfr, zero, 0, 0, 0);
            const int n0 = mtile * 16 + 4 * h4;
            const float4 g4 = *(const float4*)&pg[m][n0];
            const float4 b4 = *(const float4*)&pbe[m][n0];
            uint2 w;
            w.x = (unsigned)f2bf(fmaf((fmaxf(acc[0], 0.f) - mu) * rs, g4.x, b4.x))
                | ((unsigned)f2bf(fmaf((fmaxf(acc[1], 0.f) - mu) * rs, g4.y, b4.y)) << 16);
            w.y = (unsigned)f2bf(fmaf((fmaxf(acc[2], 0.f) - mu) * rs, g4.z, b4.z))
                | ((unsigned)f2bf(fmaf((fmaxf(acc[3], 0.f) - mu) * rs, g4.w, b4.w)) << 16);
            *(uint2*)&hnrow[n0] = w;
        }
        // pinned A-pattern read: elem j of frag s = h_n[edge l&15][32s+8h4+j]
        #pragma unroll
        for (int s = 0; s < 4; ++s)
            afr[s] = *(const bf16x8*)&hnrow[32 * s + 8 * h4];
    };

    bf16x8 afr[4];

    // ================= MLP 0: ea (attention bias, cols padded 8->16) ========
    float eaacc[4];
    first_layer(0, afr);
    {
        f32x4 acc = {0.f, 0.f, 0.f, 0.f};
        #pragma unroll
        for (int s = 0; s < 4; ++s) {
            const bf16x8 bfr = *(const bf16x8*)(easw + (size_t)(s * 64 + l) * 8);
            acc = __builtin_amdgcn_mfma_f32_16x16x32_bf16(afr[s], bfr, acc, 0, 0, 0);
        }
        #pragma unroll
        for (int r = 0; r < 4; ++r) eaacc[r] = acc[r];   // raw; bias added later
    }

    // ================= MLP 1: ek -> scores -> exp -> ex_ws ==================
    first_layer(1, afr);
    #pragma unroll
    for (int nt = 0; nt < NHEAD; ++nt) {
        f32x4 acc = {0.f, 0.f, 0.f, 0.f};
        #pragma unroll
        for (int s = 0; s < 4; ++s) {
            const bf16x8 bfr = *(const bf16x8*)(eksw + (size_t)((nt * 4 + s) * 64 + l) * 8);
            acc = __builtin_amdgcn_mfma_f32_16x16x32_bf16(afr[s], bfr, acc, 0, 0, 0);
        }
        const int col = nt * 16 + colb;
        const float b2 = pb2k[col];
        const float ba = pb2a[nt];
        float pr[4];
        #pragma unroll
        for (int r = 0; r < 4; ++r) {
            const int tnr  = et_s[mt*16 + row0 + r];
            const int hnr  = eh_s[mt*16 + row0 + r];
            pr[r] = (acc[r] + b2 + bf2f(k16[(size_t)tnr * D + col]))
                    * bf2f(q16[(size_t)hnr * D + col]);
        }
        #pragma unroll
        for (int m = 1; m < 16; m <<= 1) {
            #pragma unroll
            for (int r = 0; r < 4; ++r) pr[r] += __shfl_xor(pr[r], m);
        }
        #pragma unroll
        for (int r = 0; r < 4; ++r) {
            // segment-max skipped: |score| small, exp cannot overflow.
            const float ea = __shfl(eaacc[r], bsrc | nt);
            const float ex = __expf(pr[r] + ea + ba);
            if (colb == nt)
                ex_ws[(size_t)(e0g + mt*16 + row0 + r) * NHEAD + nt] = ex;
        }
    }

    // ================= MLP 2: ev -> raw vs (bf16) ===========================
    first_layer(2, afr);
    #pragma unroll
    for (int nt = 0; nt < NHEAD; ++nt) {
        f32x4 acc = {0.f, 0.f, 0.f, 0.f};
        #pragma unroll
        for (int s = 0; s < 4; ++s) {
            const bf16x8 bfr = *(const bf16x8*)(evsw + (size_t)((nt * 4 + s) * 64 + l) * 8);
            acc = __builtin_amdgcn_mfma_f32_16x16x32_bf16(afr[s], bfr, acc, 0, 0, 0);
        }
        const int col = nt * 16 + colb;
        const float b2 = pb2v[col];
        #pragma unroll
        for (int r = 0; r < 4; ++r) {
            const int tnr = et_s[mt*16 + row0 + r];
            const float vs = acc[r] + b2 + bf2f(v16[(size_t)tnr * D + col]);
            vs_ws[(size_t)(e0g + mt*16 + row0 + r) * D + col] = f2bf(vs);
        }
    }
}

// ---------------------------------------------------------------------------
// agg_out: 512 threads, 16 nodes per block, 4 row-groups (4 nodes each).
// Phase 1: stream each node's contiguous sorted segment of (ex, vs) -> LDS y.
// Phase 2: project y @ W + b (each row-group does 4 output rows).
// Plain bounds: no waves/EU contract (R9/R10: never squeeze the allocator).
// ---------------------------------------------------------------------------
__global__ __launch_bounds__(512) void agg_out(
    const int* __restrict__ base,
    const float* __restrict__ ex_ws, const ushort_t* __restrict__ vs_ws,
    const float* __restrict__ W, const float* __restrict__ bias,
    float* __restrict__ out)
{
    __shared__ float xs[D][20];
    const int t  = threadIdx.x;
    const int rg = t >> 7;          // 0..3: node/row group
    const int j  = t & 127;
    const int h  = j >> 4;
    const int n0 = blockIdx.x * 16;

    // ---- phase 1: per-node segmented reduction (contiguous, no indices) ----
    #pragma unroll
    for (int ni = 0; ni < 4; ++ni) {
        const int n  = n0 + rg * 4 + ni;
        const int s0 = base[n], s1 = base[n + 1];
        float acc = 0.f, den = 0.f;
        int p = s0;
        for (; p + 4 <= s1; p += 4) {
            float ex4[4], vs4[4];
            #pragma unroll
            for (int r = 0; r < 4; ++r) {
                ex4[r] = ex_ws[(size_t)(p + r) * NHEAD + h];
                vs4[r] = bf2f(vs_ws[(size_t)(p + r) * D + j]);
            }
            #pragma unroll
            for (int r = 0; r < 4; ++r) {
                den += ex4[r];
                acc = fmaf(ex4[r], vs4[r], acc);
            }
        }
        for (; p < s1; ++p) {
            const float ex = ex_ws[(size_t)p * NHEAD + h];
            den += ex;
            acc = fmaf(ex, bf2f(vs_ws[(size_t)p * D + j]), acc);
        }
        xs[j][rg * 4 + ni] = acc / (den + EPS_SM);
    }
    __syncthreads();

    // ---- phase 2: out projection; row-group rg does rows rg*4..rg*4+4 ------
    float acc[4];
    const float b = bias[j];
    #pragma unroll
    for (int r = 0; r < 4; ++r) acc[r] = b;
    #pragma unroll 4
    for (int i = 0; i < D; ++i) {
        const float w = W[i * D + j];
        const float4 y4 = *(const float4*)&xs[i][rg * 4];
        acc[0] = fmaf(y4.x, w, acc[0]); acc[1] = fmaf(y4.y, w, acc[1]);
        acc[2] = fmaf(y4.z, w, acc[2]); acc[3] = fmaf(y4.w, w, acc[3]);
    }
    #pragma unroll
    for (int r = 0; r < 4; ++r)
        out[(size_t)(n0 + rg * 4 + r) * D + j] = acc[r];
}

// ---------------------------------------------------------------------------
extern "C" void kernel_launch(void* const* d_in, const int* in_sizes, int n_in,
                              void* d_out, int out_size, void* d_ws, size_t ws_size,
                              hipStream_t stream)
{
    const float* key        = (const float*)d_in[0];
    const float* value      = (const float*)d_in[1];
    const float* query      = (const float*)d_in[2];
    const float* edge_feats = (const float*)d_in[3];
    const int*   bidx       = (const int*)d_in[5];
    const int*   hidx       = (const int*)d_in[6];
    const int*   tidx       = (const int*)d_in[7];
    const float* key_w   = (const float*)d_in[8];  const float* key_b   = (const float*)d_in[9];
    const float* query_w = (const float*)d_in[10]; const float* query_b = (const float*)d_in[11];
    const float* value_w = (const float*)d_in[12]; const float* value_b = (const float*)d_in[13];
    const float* proj_w  = (const float*)d_in[14]; const float* proj_b  = (const float*)d_in[15];

    const int N = in_sizes[0] / D;   // 16384 nodes
    const int E = in_sizes[5];       // 262144 edges

    char* ws = (char*)d_ws;
    ushort_t* k16   = (ushort_t*)ws; ws += (size_t)N * D * 2;
    ushort_t* q16   = (ushort_t*)ws; ws += (size_t)N * D * 2;
    ushort_t* v16   = (ushort_t*)ws; ws += (size_t)N * D * 2;
    float* ex_ws    = (float*)ws;    ws += (size_t)E * NHEAD * 4;
    ushort_t* vs_ws = (ushort_t*)ws; ws += (size_t)E * D * 2;
    float* rec      = (float*)ws;    ws += (size_t)E * 8 * 4;
    ushort_t* eksw  = (ushort_t*)ws; ws += (size_t)2048 * 8 * 2;
    ushort_t* evsw  = (ushort_t*)ws; ws += (size_t)2048 * 8 * 2;
    ushort_t* easw  = (ushort_t*)ws; ws += (size_t)256 * 8 * 2;
    ushort_t* kwsw  = (ushort_t*)ws; ws += (size_t)2048 * 8 * 2;
    ushort_t* qwsw  = (ushort_t*)ws; ws += (size_t)2048 * 8 * 2;
    ushort_t* vwsw  = (ushort_t*)ws; ws += (size_t)2048 * 8 * 2;
    ushort_t* w1fg  = (ushort_t*)ws; ws += (size_t)1536 * 8 * 2;
    int* base = (int*)ws;  ws += (size_t)(N + 1) * 4;
    int* cnt  = (int*)ws;  ws += (size_t)N * 4;

    const int nqm   = N / 64;             // MFMA-qkv blocks per matrix (256)
    const int nhist = (E + 255) / 256;    // 1024

    hipMemsetAsync(cnt, 0, (size_t)N * 4, stream);

    pre_kernel<<<47 + nhist, 256, 0, stream>>>(
        (const float*)d_in[26], (const float*)d_in[32], (const float*)d_in[20],
        key_w, query_w, value_w,
        (const float*)d_in[16], (const float*)d_in[17],
        (const float*)d_in[22], (const float*)d_in[23],
        (const float*)d_in[28], (const float*)d_in[29],
        eksw, evsw, easw, kwsw, qwsw, vwsw, w1fg,
        bidx, hidx, cnt, E);

    scan16k<<<1, 1024, 0, stream>>>(cnt, base);

    mid_kernel<<<3 * nqm + nhist, 256, 0, stream>>>(
        key, value, query,
        key_b, value_b, query_b,
        kwsw, vwsw, qwsw,
        k16, v16, q16,
        bidx, hidx, tidx, edge_feats,
        base, cnt, rec, nqm, E);

    edge_kernel<<<E / EPB, 256, 0, stream>>>(
        rec, w1fg,
        (const float*)d_in[18], (const float*)d_in[19], (const float*)d_in[21],
        (const float*)d_in[24], (const float*)d_in[25], (const float*)d_in[27],
        (const float*)d_in[30], (const float*)d_in[31], (const float*)d_in[33],
        easw, eksw, evsw,
        k16, q16, v16,
        ex_ws, vs_ws);

    agg_out<<<N / 16, 512, 0, stream>>>(base, ex_ws, vs_ws, proj_w, proj_b, (float*)d_out);
}

// Round 6
// 319.529 us; speedup vs baseline: 1.2855x; 1.1490x over previous
//
#include <hip/hip_runtime.h>
#include <hip/hip_bf16.h>

#define D      128
#define NHEAD  8
#define FE     5
#define LSEQ   4096
#define EPB    64          // edges per block in edge_kernel
#define NNODE  16384
#define EPS_LN 1e-5f
#define EPS_SM 1e-16f

typedef unsigned short ushort_t;
typedef __bf16 bf16x8 __attribute__((ext_vector_type(8)));
typedef float  f32x4  __attribute__((ext_vector_type(4)));

__device__ __forceinline__ ushort_t f2bf(float x) {
    __hip_bfloat16 b = __float2bfloat16(x);
    return __builtin_bit_cast(unsigned short, b);
}
__device__ __forceinline__ float bf2f(ushort_t u) {
    __hip_bfloat16 b = __builtin_bit_cast(__hip_bfloat16, u);
    return __bfloat162float(b);
}
__device__ __forceinline__ float i2f(int x)  { return __builtin_bit_cast(float, x); }
__device__ __forceinline__ int   f2i(float x){ return __builtin_bit_cast(int, x); }

union Pk8 { ushort_t u[8]; uint4 v; };

// ---------------------------------------------------------------------------
// pre_kernel:
//   blocks [0,47)    : swizzle weights into bf16 MFMA frag layouts
//     g <  10496 : B-frags for ek_w2, ev_w2, ea_w2, key_w, query_w, value_w
//     g >= 10496 : A-frags for layer-1 W1^T (3 MLPs), NATURAL neuron order
//       (neuron = mt*16 + mi). K-space layout (hi/lo split + bias fold,
//       f32-accurate layer-1):
//         kf[0,5)=W_hi (pairs ef_hi), kf[8,13)=W_hi (pairs ef_lo),
//         kf[16,21)=W_lo (pairs ef_hi), kf24/25=b1_hi/b1_lo (pair 1.0).
//   blocks [47,+1024): head histogram (cnt pre-zeroed by memset)
// ---------------------------------------------------------------------------
__global__ __launch_bounds__(256) void pre_kernel(
    const float* __restrict__ ekw2, const float* __restrict__ evw2,
    const float* __restrict__ eaw2,
    const float* __restrict__ kw, const float* __restrict__ qw,
    const float* __restrict__ vw,
    const float* __restrict__ eaw1, const float* __restrict__ eab1,
    const float* __restrict__ ekw1, const float* __restrict__ ekb1,
    const float* __restrict__ evw1, const float* __restrict__ evb1,
    ushort_t* __restrict__ eksw, ushort_t* __restrict__ evsw, ushort_t* __restrict__ easw,
    ushort_t* __restrict__ kwsw, ushort_t* __restrict__ qwsw, ushort_t* __restrict__ vwsw,
    ushort_t* __restrict__ w1fg,
    const int* __restrict__ bidx, const int* __restrict__ hidx,
    int* __restrict__ cnt, int E)
{
    const int t = threadIdx.x;
    if (blockIdx.x < 47) {
        const int g = blockIdx.x * 256 + t;
        if (g < 10496) {
            const float* src; ushort_t* dst; int frag, ncols = 128, nvalid = 128;
            if (g < 2048)       { src = ekw2; dst = eksw; frag = g; }
            else if (g < 4096)  { src = evw2; dst = evsw; frag = g - 2048; }
            else if (g < 4352)  { src = eaw2; dst = easw; frag = g - 4096; ncols = 8; nvalid = 8; }
            else if (g < 6400)  { src = kw;   dst = kwsw; frag = g - 4352; }
            else if (g < 8448)  { src = qw;   dst = qwsw; frag = g - 6400; }
            else                { src = vw;   dst = vwsw; frag = g - 8448; }
            const int s = (frag >> 6) & 3;
            const int l = frag & 63;
            const int n = ((frag >> 8) << 4) + (l & 15);
            Pk8 pk;
            #pragma unroll
            for (int j = 0; j < 8; ++j) {
                const int k = s * 32 + (l >> 4) * 8 + j;
                const float v = (n < nvalid) ? src[k * ncols + n] : 0.f;
                pk.u[j] = f2bf(v);
            }
            *(uint4*)(dst + (size_t)frag * 8) = pk.v;
            return;
        }
        // ---- layer-1 A-frags (W1^T, natural order, bias-folded, hi/lo) -----
        const int g2  = g - 10496;          // [0, 1536)
        const int mlp = g2 >> 9;            // 0:ea 1:ek 2:ev
        const int q   = g2 & 511;
        const int mt  = q >> 6;             // output-dim tile
        const int l   = q & 63;             // lane
        const int mi  = l & 15;             // within-tile output row (A row)
        const int gk  = l >> 4;             // k-group
        const float* w1 = (mlp == 0) ? eaw1 : (mlp == 1) ? ekw1 : evw1;
        const float* b1 = (mlp == 0) ? eab1 : (mlp == 1) ? ekb1 : evb1;
        const int neuron = mt * 16 + mi;    // NATURAL order
        Pk8 pk;
        #pragma unroll
        for (int j = 0; j < 8; ++j) {
            const int kf = gk * 8 + j;
            float v = 0.f; bool lo = false;
            if (kf < FE)                            v = w1[kf * D + neuron];
            else if (kf >= 8  && kf < 8  + FE)      v = w1[(kf - 8) * D + neuron];
            else if (kf >= 16 && kf < 16 + FE)    { v = w1[(kf - 16) * D + neuron]; lo = true; }
            else if (kf == 24)                      v = b1[neuron];
            else if (kf == 25)                    { v = b1[neuron]; lo = true; }
            const ushort_t hi = f2bf(v);
            pk.u[j] = lo ? f2bf(v - bf2f(hi)) : hi;
        }
        *(uint4*)(w1fg + (size_t)g2 * 8) = pk.v;
        return;
    }
    // ---------------- histogram ------------------------------------------
    const int e = (blockIdx.x - 47) * 256 + t;
    if (e < E) atomicAdd(&cnt[bidx[e] * LSEQ + hidx[e]], 1);
}

// ---------------------------------------------------------------------------
// Exclusive scan of the 16384-bin histogram (single block, ~5 µs).
// ---------------------------------------------------------------------------
__global__ __launch_bounds__(1024) void scan16k(
    const int* __restrict__ cnt, int* __restrict__ base)
{
    __shared__ int part[1024];
    const int t = threadIdx.x;
    int v[16], ex[16], s = 0;
    #pragma unroll
    for (int i = 0; i < 16; ++i) v[i] = cnt[t * 16 + i];
    #pragma unroll
    for (int i = 0; i < 16; ++i) { ex[i] = s; s += v[i]; }
    part[t] = s;
    __syncthreads();
    for (int off = 1; off < 1024; off <<= 1) {
        const int x = (t >= off) ? part[t - off] : 0;
        __syncthreads();
        part[t] += x;
        __syncthreads();
    }
    const int boff = (t > 0) ? part[t - 1] : 0;
    #pragma unroll
    for (int i = 0; i < 16; ++i) base[t * 16 + i] = boff + ex[i];
    if (t == 1023) base[NNODE] = boff + s;
}

// ---------------------------------------------------------------------------
// mid_kernel: two independent jobs overlapped in one dispatch:
//   blocks [0, 3*nqm)  : MFMA qkv GEMMs, 64 rows/block, bf16 out.
//   blocks [3*nqm, +)  : scatter_rec — sorted slot p per edge, packed 32 B
//                        record rec[p] = {ef[5], head, tail, pad}.
// ---------------------------------------------------------------------------
__global__ __launch_bounds__(256) void mid_kernel(
    const float* __restrict__ key, const float* __restrict__ value,
    const float* __restrict__ query,
    const float* __restrict__ key_b, const float* __restrict__ value_b,
    const float* __restrict__ query_b,
    const ushort_t* __restrict__ kwsw, const ushort_t* __restrict__ vwsw,
    const ushort_t* __restrict__ qwsw,
    ushort_t* __restrict__ k16, ushort_t* __restrict__ v16, ushort_t* __restrict__ q16,
    const int* __restrict__ bidx, const int* __restrict__ hidx, const int* __restrict__ tidx,
    const float* __restrict__ edge_feats,
    const int* __restrict__ base, int* __restrict__ cnt, float* __restrict__ rec,
    int nqm, int E)
{
    const int t  = threadIdx.x;
    const int nq = 3 * nqm;
    if ((int)blockIdx.x < nq) {
        const int which = blockIdx.x / nqm;
        const int blk   = blockIdx.x % nqm;
        const float* X     = (which == 0) ? key   : (which == 1) ? value   : query;
        const float* bias  = (which == 0) ? key_b : (which == 1) ? value_b : query_b;
        const ushort_t* Ww = (which == 0) ? kwsw  : (which == 1) ? vwsw    : qwsw;
        ushort_t* Y        = (which == 0) ? k16   : (which == 1) ? v16     : q16;

        const int mt    = t >> 6;
        const int l     = t & 63;
        const int rbase = blk * 64 + mt * 16;
        const int colb  = l & 15;
        const int row0  = (l >> 4) * 4;
        const int arow  = rbase + colb;        // A row for this lane (m = l&15)
        const int koff  = (l >> 4) * 8;        // k-offset within 32-chunk

        bf16x8 afr[4];
        #pragma unroll
        for (int s = 0; s < 4; ++s) {
            const float4 x0 = *(const float4*)&X[(size_t)arow * D + s * 32 + koff];
            const float4 x1 = *(const float4*)&X[(size_t)arow * D + s * 32 + koff + 4];
            Pk8 p8;
            p8.u[0] = f2bf(x0.x); p8.u[1] = f2bf(x0.y);
            p8.u[2] = f2bf(x0.z); p8.u[3] = f2bf(x0.w);
            p8.u[4] = f2bf(x1.x); p8.u[5] = f2bf(x1.y);
            p8.u[6] = f2bf(x1.z); p8.u[7] = f2bf(x1.w);
            afr[s] = __builtin_bit_cast(bf16x8, p8.v);
        }
        #pragma unroll
        for (int nt = 0; nt < 8; ++nt) {
            f32x4 acc = {0.f, 0.f, 0.f, 0.f};
            #pragma unroll
            for (int s = 0; s < 4; ++s) {
                const bf16x8 bfr = *(const bf16x8*)(Ww + (size_t)((nt * 4 + s) * 64 + l) * 8);
                acc = __builtin_amdgcn_mfma_f32_16x16x32_bf16(afr[s], bfr, acc, 0, 0, 0);
            }
            const int col = nt * 16 + colb;
            const float b = bias[col];
            #pragma unroll
            for (int r = 0; r < 4; ++r)
                Y[(size_t)(rbase + row0 + r) * D + col] = f2bf(acc[r] + b);
        }
        return;
    }

    // ---------------- scatter_rec ----------------------------------------
    const int e = (blockIdx.x - nq) * 256 + t;
    if (e >= E) return;
    const int bb = bidx[e];
    const int nh = bb * LSEQ + hidx[e];
    const int nt = bb * LSEQ + tidx[e];
    const int slot = atomicSub(&cnt[nh], 1) - 1;
    const int p = base[nh] + slot;
    float ef[FE];
    #pragma unroll
    for (int f = 0; f < FE; ++f) ef[f] = edge_feats[(size_t)e * FE + f];
    *(float4*)&rec[(size_t)p * 8]     = float4{ef[0], ef[1], ef[2], ef[3]};
    *(float4*)&rec[(size_t)p * 8 + 4] = float4{ef[4], i2f(nh), i2f(nt), 0.f};
}

// ---------------------------------------------------------------------------
// Fused edge kernel — EXACT R13 (Round-3 PASSED) structure: layer-1 frags
// read from GLOBAL w1fg (LDS-staging of w1f failed 3/3 attempts at ~1e-2
// absmax across 3 independent implementations — R1/R4/R5 — mechanism
// unexplained; global path passed 2/2 — do NOT re-stage w1f in LDS).
// R16 changes vs R13, both scheduling/allocation-only (per-lane instruction
// content and FP order identical to the twice-passed code):
//   (1) #pragma unroll 2 on the two mtile loops: caps in-flight global
//       w1fg loads at 2 (8 VGPRs) instead of 8 (32 VGPRs) — R13's 43-dword
//       /thread scratch spill (WRITE 264 MB) was the compiler clustering
//       the fully-unrolled ~500-cyc loads into a hoisted live range.
//   (2) __launch_bounds__(256,3): 170 unified regs/wave (vs 128) as
//       insurance; LDS 23.5 KB so occupancy stays allocator-limited.
// ---------------------------------------------------------------------------
__global__ __launch_bounds__(256, 3) void edge_kernel(
    const float* __restrict__ rec,
    const ushort_t* __restrict__ w1fg,
    const float* __restrict__ ea_g,  const float* __restrict__ ea_be, const float* __restrict__ ea_b2,
    const float* __restrict__ ek_g,  const float* __restrict__ ek_be, const float* __restrict__ ek_b2,
    const float* __restrict__ ev_g,  const float* __restrict__ ev_be, const float* __restrict__ ev_b2,
    const ushort_t* __restrict__ easw, const ushort_t* __restrict__ eksw, const ushort_t* __restrict__ evsw,
    const ushort_t* __restrict__ k16, const ushort_t* __restrict__ q16, const ushort_t* __restrict__ v16,
    float* __restrict__ ex_ws, ushort_t* __restrict__ vs_ws)
{
    __shared__ ushort_t hn[4][16][136];     // 17 KB wave-local h_n round-trip
    __shared__ float pg[3][D], pbe[3][D];
    __shared__ float pb2k[D], pb2v[D], pb2a[NHEAD];
    __shared__ float ef_s[EPB][FE];
    __shared__ int   eh_s[EPB], et_s[EPB];

    const int t   = threadIdx.x;
    const int e0g = blockIdx.x * EPB;   // sorted-position base

    if (t < D) {
        pg [0][t] = ea_g [t]; pg [1][t] = ek_g [t]; pg [2][t] = ev_g [t];
        pbe[0][t] = ea_be[t]; pbe[1][t] = ek_be[t]; pbe[2][t] = ev_be[t];
        pb2k[t] = ek_b2[t];   pb2v[t] = ev_b2[t];
        if (t < NHEAD) pb2a[t] = ea_b2[t];
    }
    if (t < 128) {
        const int pl = t >> 1, half = t & 1;
        const float4 v = *(const float4*)&rec[((size_t)e0g + pl) * 8 + half * 4];
        if (half == 0) {
            ef_s[pl][0] = v.x; ef_s[pl][1] = v.y; ef_s[pl][2] = v.z; ef_s[pl][3] = v.w;
        } else {
            ef_s[pl][4] = v.x; eh_s[pl] = f2i(v.y); et_s[pl] = f2i(v.z);
        }
    }
    __syncthreads();     // the only barrier

    const int mt   = t >> 6;        // wave id == m-tile (16 edges per wave)
    const int l    = t & 63;        // lane
    const int h4   = l >> 4;        // k-group / h-group
    const int row0 = h4 * 4;        // consumer: accumulator row base
    const int colb = l & 15;        // consumer: column within n-tile
    const int bsrc = (l & 48);      // row-group base for ea broadcasts

    // ---- shared layer-1 B operand: X^T frag (edge = l&15), hi/lo + bias ----
    bf16x8 xfr;
    {
        const float* e = ef_s[mt * 16 + colb];
        Pk8 xf;
        if (h4 == 3) {
            const ushort_t one = f2bf(1.f);
            xf.u[0] = one; xf.u[1] = one;
            #pragma unroll
            for (int j = 2; j < 8; ++j) xf.u[j] = 0;
        } else {
            #pragma unroll
            for (int f = 0; f < FE; ++f) {
                const float v = e[f];
                const ushort_t hi = f2bf(v);
                xf.u[f] = (h4 == 1) ? f2bf(v - bf2f(hi)) : hi;
            }
            xf.u[5] = 0; xf.u[6] = 0; xf.u[7] = 0;
        }
        xfr = __builtin_bit_cast(bf16x8, xf.v);
    }

    ushort_t* hnrow = &hn[mt][colb][0];     // this lane's edge row (wave-local)

    // layer-1 via two-pass MFMA; h_n lands in afr[] via the LDS round-trip.
    auto first_layer = [&](int m, bf16x8 afr[4]) {
        const f32x4 zero = {0.f, 0.f, 0.f, 0.f};
        float s1 = 0.f, s2 = 0.f;
        // pass 1: LN statistics only; acc dies each iteration.
        // unroll 2: cap in-flight global loads (R13 spill fix).
        #pragma unroll 2
        for (int mtile = 0; mtile < 8; ++mtile) {
            const bf16x8 aw = *(const bf16x8*)(w1fg + (size_t)((m * 8 + mtile) * 64 + l) * 8);
            const f32x4 acc = __builtin_amdgcn_mfma_f32_16x16x32_bf16(aw, xfr, zero, 0, 0, 0);
            #pragma unroll
            for (int r = 0; r < 4; ++r) {
                const float v = fmaxf(acc[r], 0.f);
                s1 += v; s2 += v * v;
            }
        }
        s1 += __shfl_xor(s1, 16); s1 += __shfl_xor(s1, 32);
        s2 += __shfl_xor(s2, 16); s2 += __shfl_xor(s2, 32);
        const float mu = s1 * (1.f / 128.f);
        const float rs = rsqrtf(s2 * (1.f / 128.f) - mu * mu + EPS_LN);
        // pass 2: recompute, normalize, store to wave-local LDS (D-layout:
        // lane holds rows 4*h4+r of m-tile mtile for edge colb; natural
        // neuron = mtile*16 + 4*h4 + r).
        #pragma unroll 2
        for (int mtile = 0; mtile < 8; ++mtile) {
            const bf16x8 aw = *(const bf16x8*)(w1fg + (size_t)((m * 8 + mtile) * 64 + l) * 8);
            const f32x4 acc = __builtin_amdgcn_mfma_f32_16x16x32_bf16(aw, xfr, zero, 0, 0, 0);
            const int n0 = mtile * 16 + 4 * h4;
            const float4 g4 = *(const float4*)&pg[m][n0];
            const float4 b4 = *(const float4*)&pbe[m][n0];
            uint2 w;
            w.x = (unsigned)f2bf(fmaf((fmaxf(acc[0], 0.f) - mu) * rs, g4.x, b4.x))
                | ((unsigned)f2bf(fmaf((fmaxf(acc[1], 0.f) - mu) * rs, g4.y, b4.y)) << 16);
            w.y = (unsigned)f2bf(fmaf((fmaxf(acc[2], 0.f) - mu) * rs, g4.z, b4.z))
                | ((unsigned)f2bf(fmaf((fmaxf(acc[3], 0.f) - mu) * rs, g4.w, b4.w)) << 16);
            *(uint2*)&hnrow[n0] = w;
        }
        // pinned A-pattern read: elem j of frag s = h_n[edge l&15][32s+8h4+j]
        #pragma unroll
        for (int s = 0; s < 4; ++s)
            afr[s] = *(const bf16x8*)&hnrow[32 * s + 8 * h4];
    };

    bf16x8 afr[4];

    // ================= MLP 0: ea (attention bias, cols padded 8->16) ========
    float eaacc[4];
    first_layer(0, afr);
    {
        f32x4 acc = {0.f, 0.f, 0.f, 0.f};
        #pragma unroll
        for (int s = 0; s < 4; ++s) {
            const bf16x8 bfr = *(const bf16x8*)(easw + (size_t)(s * 64 + l) * 8);
            acc = __builtin_amdgcn_mfma_f32_16x16x32_bf16(afr[s], bfr, acc, 0, 0, 0);
        }
        #pragma unroll
        for (int r = 0; r < 4; ++r) eaacc[r] = acc[r];   // raw; bias added later
    }

    // ================= MLP 1: ek -> scores -> exp -> ex_ws ==================
    first_layer(1, afr);
    #pragma unroll
    for (int nt = 0; nt < NHEAD; ++nt) {
        f32x4 acc = {0.f, 0.f, 0.f, 0.f};
        #pragma unroll
        for (int s = 0; s < 4; ++s) {
            const bf16x8 bfr = *(const bf16x8*)(eksw + (size_t)((nt * 4 + s) * 64 + l) * 8);
            acc = __builtin_amdgcn_mfma_f32_16x16x32_bf16(afr[s], bfr, acc, 0, 0, 0);
        }
        const int col = nt * 16 + colb;
        const float b2 = pb2k[col];
        const float ba = pb2a[nt];
        float pr[4];
        #pragma unroll
        for (int r = 0; r < 4; ++r) {
            const int tnr  = et_s[mt*16 + row0 + r];
            const int hnr  = eh_s[mt*16 + row0 + r];
            pr[r] = (acc[r] + b2 + bf2f(k16[(size_t)tnr * D + col]))
                    * bf2f(q16[(size_t)hnr * D + col]);
        }
        #pragma unroll
        for (int m = 1; m < 16; m <<= 1) {
            #pragma unroll
            for (int r = 0; r < 4; ++r) pr[r] += __shfl_xor(pr[r], m);
        }
        #pragma unroll
        for (int r = 0; r < 4; ++r) {
            // segment-max skipped: |score| small, exp cannot overflow.
            const float ea = __shfl(eaacc[r], bsrc | nt);
            const float ex = __expf(pr[r] + ea + ba);
            if (colb == nt)
                ex_ws[(size_t)(e0g + mt*16 + row0 + r) * NHEAD + nt] = ex;
        }
    }

    // ================= MLP 2: ev -> raw vs (bf16) ===========================
    first_layer(2, afr);
    #pragma unroll
    for (int nt = 0; nt < NHEAD; ++nt) {
        f32x4 acc = {0.f, 0.f, 0.f, 0.f};
        #pragma unroll
        for (int s = 0; s < 4; ++s) {
            const bf16x8 bfr = *(const bf16x8*)(evsw + (size_t)((nt * 4 + s) * 64 + l) * 8);
            acc = __builtin_amdgcn_mfma_f32_16x16x32_bf16(afr[s], bfr, acc, 0, 0, 0);
        }
        const int col = nt * 16 + colb;
        const float b2 = pb2v[col];
        #pragma unroll
        for (int r = 0; r < 4; ++r) {
            const int tnr = et_s[mt*16 + row0 + r];
            const float vs = acc[r] + b2 + bf2f(v16[(size_t)tnr * D + col]);
            vs_ws[(size_t)(e0g + mt*16 + row0 + r) * D + col] = f2bf(vs);
        }
    }
}

// ---------------------------------------------------------------------------
// agg_out: 512 threads, 16 nodes per block, 4 row-groups (4 nodes each).
// Phase 1: stream each node's contiguous sorted segment of (ex, vs) -> LDS y.
// Phase 2: project y @ W + b (each row-group does 4 output rows).
// Plain bounds: no waves/EU contract (R9/R10: never squeeze the allocator).
// ---------------------------------------------------------------------------
__global__ __launch_bounds__(512) void agg_out(
    const int* __restrict__ base,
    const float* __restrict__ ex_ws, const ushort_t* __restrict__ vs_ws,
    const float* __restrict__ W, const float* __restrict__ bias,
    float* __restrict__ out)
{
    __shared__ float xs[D][20];
    const int t  = threadIdx.x;
    const int rg = t >> 7;          // 0..3: node/row group
    const int j  = t & 127;
    const int h  = j >> 4;
    const int n0 = blockIdx.x * 16;

    // ---- phase 1: per-node segmented reduction (contiguous, no indices) ----
    #pragma unroll
    for (int ni = 0; ni < 4; ++ni) {
        const int n  = n0 + rg * 4 + ni;
        const int s0 = base[n], s1 = base[n + 1];
        float acc = 0.f, den = 0.f;
        int p = s0;
        for (; p + 4 <= s1; p += 4) {
            float ex4[4], vs4[4];
            #pragma unroll
            for (int r = 0; r < 4; ++r) {
                ex4[r] = ex_ws[(size_t)(p + r) * NHEAD + h];
                vs4[r] = bf2f(vs_ws[(size_t)(p + r) * D + j]);
            }
            #pragma unroll
            for (int r = 0; r < 4; ++r) {
                den += ex4[r];
                acc = fmaf(ex4[r], vs4[r], acc);
            }
        }
        for (; p < s1; ++p) {
            const float ex = ex_ws[(size_t)p * NHEAD + h];
            den += ex;
            acc = fmaf(ex, bf2f(vs_ws[(size_t)p * D + j]), acc);
        }
        xs[j][rg * 4 + ni] = acc / (den + EPS_SM);
    }
    __syncthreads();

    // ---- phase 2: out projection; row-group rg does rows rg*4..rg*4+4 ------
    float acc[4];
    const float b = bias[j];
    #pragma unroll
    for (int r = 0; r < 4; ++r) acc[r] = b;
    #pragma unroll 4
    for (int i = 0; i < D; ++i) {
        const float w = W[i * D + j];
        const float4 y4 = *(const float4*)&xs[i][rg * 4];
        acc[0] = fmaf(y4.x, w, acc[0]); acc[1] = fmaf(y4.y, w, acc[1]);
        acc[2] = fmaf(y4.z, w, acc[2]); acc[3] = fmaf(y4.w, w, acc[3]);
    }
    #pragma unroll
    for (int r = 0; r < 4; ++r)
        out[(size_t)(n0 + rg * 4 + r) * D + j] = acc[r];
}

// ---------------------------------------------------------------------------
extern "C" void kernel_launch(void* const* d_in, const int* in_sizes, int n_in,
                              void* d_out, int out_size, void* d_ws, size_t ws_size,
                              hipStream_t stream)
{
    const float* key        = (const float*)d_in[0];
    const float* value      = (const float*)d_in[1];
    const float* query      = (const float*)d_in[2];
    const float* edge_feats = (const float*)d_in[3];
    const int*   bidx       = (const int*)d_in[5];
    const int*   hidx       = (const int*)d_in[6];
    const int*   tidx       = (const int*)d_in[7];
    const float* key_w   = (const float*)d_in[8];  const float* key_b   = (const float*)d_in[9];
    const float* query_w = (const float*)d_in[10]; const float* query_b = (const float*)d_in[11];
    const float* value_w = (const float*)d_in[12]; const float* value_b = (const float*)d_in[13];
    const float* proj_w  = (const float*)d_in[14]; const float* proj_b  = (const float*)d_in[15];

    const int N = in_sizes[0] / D;   // 16384 nodes
    const int E = in_sizes[5];       // 262144 edges

    char* ws = (char*)d_ws;
    ushort_t* k16   = (ushort_t*)ws; ws += (size_t)N * D * 2;
    ushort_t* q16   = (ushort_t*)ws; ws += (size_t)N * D * 2;
    ushort_t* v16   = (ushort_t*)ws; ws += (size_t)N * D * 2;
    float* ex_ws    = (float*)ws;    ws += (size_t)E * NHEAD * 4;
    ushort_t* vs_ws = (ushort_t*)ws; ws += (size_t)E * D * 2;
    float* rec      = (float*)ws;    ws += (size_t)E * 8 * 4;
    ushort_t* eksw  = (ushort_t*)ws; ws += (size_t)2048 * 8 * 2;
    ushort_t* evsw  = (ushort_t*)ws; ws += (size_t)2048 * 8 * 2;
    ushort_t* easw  = (ushort_t*)ws; ws += (size_t)256 * 8 * 2;
    ushort_t* kwsw  = (ushort_t*)ws; ws += (size_t)2048 * 8 * 2;
    ushort_t* qwsw  = (ushort_t*)ws; ws += (size_t)2048 * 8 * 2;
    ushort_t* vwsw  = (ushort_t*)ws; ws += (size_t)2048 * 8 * 2;
    ushort_t* w1fg  = (ushort_t*)ws; ws += (size_t)1536 * 8 * 2;
    int* base = (int*)ws;  ws += (size_t)(N + 1) * 4;
    int* cnt  = (int*)ws;  ws += (size_t)N * 4;

    const int nqm   = N / 64;             // MFMA-qkv blocks per matrix (256)
    const int nhist = (E + 255) / 256;    // 1024

    hipMemsetAsync(cnt, 0, (size_t)N * 4, stream);

    pre_kernel<<<47 + nhist, 256, 0, stream>>>(
        (const float*)d_in[26], (const float*)d_in[32], (const float*)d_in[20],
        key_w, query_w, value_w,
        (const float*)d_in[16], (const float*)d_in[17],
        (const float*)d_in[22], (const float*)d_in[23],
        (const float*)d_in[28], (const float*)d_in[29],
        eksw, evsw, easw, kwsw, qwsw, vwsw, w1fg,
        bidx, hidx, cnt, E);

    scan16k<<<1, 1024, 0, stream>>>(cnt, base);

    mid_kernel<<<3 * nqm + nhist, 256, 0, stream>>>(
        key, value, query,
        key_b, value_b, query_b,
        kwsw, vwsw, qwsw,
        k16, v16, q16,
        bidx, hidx, tidx, edge_feats,
        base, cnt, rec, nqm, E);

    edge_kernel<<<E / EPB, 256, 0, stream>>>(
        rec, w1fg,
        (const float*)d_in[18], (const float*)d_in[19], (const float*)d_in[21],
        (const float*)d_in[24], (const float*)d_in[25], (const float*)d_in[27],
        (const float*)d_in[30], (const float*)d_in[31], (const float*)d_in[33],
        easw, eksw, evsw,
        k16, q16, v16,
        ex_ws, vs_ws);

    agg_out<<<N / 16, 512, 0, stream>>>(base, ex_ws, vs_ws, proj_w, proj_b, (float*)d_out);
}

// Round 7
// 297.059 us; speedup vs baseline: 1.3827x; 1.0756x over previous
//
#include <hip/hip_runtime.h>
#include <hip/hip_bf16.h>

#define D      128
#define NHEAD  8
#define FE     5
#define LSEQ   4096
#define EPB    64          // edges per block in edge_kernel
#define NNODE  16384
#define EPS_LN 1e-5f
#define EPS_SM 1e-16f

typedef unsigned short ushort_t;
typedef __bf16 bf16x8 __attribute__((ext_vector_type(8)));
typedef float  f32x4  __attribute__((ext_vector_type(4)));

__device__ __forceinline__ ushort_t f2bf(float x) {
    __hip_bfloat16 b = __float2bfloat16(x);
    return __builtin_bit_cast(unsigned short, b);
}
__device__ __forceinline__ float bf2f(ushort_t u) {
    __hip_bfloat16 b = __builtin_bit_cast(__hip_bfloat16, u);
    return __bfloat162float(b);
}
__device__ __forceinline__ float i2f(int x)  { return __builtin_bit_cast(float, x); }
__device__ __forceinline__ int   f2i(float x){ return __builtin_bit_cast(int, x); }

union Pk8 { ushort_t u[8]; uint4 v; };

// ---------------------------------------------------------------------------
// pre_kernel:
//   blocks [0,47)    : swizzle weights into bf16 MFMA frag layouts
//     g <  10496 : B-frags for ek_w2, ev_w2, ea_w2, key_w, query_w, value_w
//     g >= 10496 : A-frags for layer-1 W1^T (3 MLPs), NATURAL neuron order
//       (neuron = mt*16 + mi). K-space layout (hi/lo split + bias fold,
//       f32-accurate layer-1):
//         kf[0,5)=W_hi (pairs ef_hi), kf[8,13)=W_hi (pairs ef_lo),
//         kf[16,21)=W_lo (pairs ef_hi), kf24/25=b1_hi/b1_lo (pair 1.0).
//   blocks [47,+1024): head histogram (cnt pre-zeroed by memset)
// ---------------------------------------------------------------------------
__global__ __launch_bounds__(256) void pre_kernel(
    const float* __restrict__ ekw2, const float* __restrict__ evw2,
    const float* __restrict__ eaw2,
    const float* __restrict__ kw, const float* __restrict__ qw,
    const float* __restrict__ vw,
    const float* __restrict__ eaw1, const float* __restrict__ eab1,
    const float* __restrict__ ekw1, const float* __restrict__ ekb1,
    const float* __restrict__ evw1, const float* __restrict__ evb1,
    ushort_t* __restrict__ eksw, ushort_t* __restrict__ evsw, ushort_t* __restrict__ easw,
    ushort_t* __restrict__ kwsw, ushort_t* __restrict__ qwsw, ushort_t* __restrict__ vwsw,
    ushort_t* __restrict__ w1fg,
    const int* __restrict__ bidx, const int* __restrict__ hidx,
    int* __restrict__ cnt, int E)
{
    const int t = threadIdx.x;
    if (blockIdx.x < 47) {
        const int g = blockIdx.x * 256 + t;
        if (g < 10496) {
            const float* src; ushort_t* dst; int frag, ncols = 128, nvalid = 128;
            if (g < 2048)       { src = ekw2; dst = eksw; frag = g; }
            else if (g < 4096)  { src = evw2; dst = evsw; frag = g - 2048; }
            else if (g < 4352)  { src = eaw2; dst = easw; frag = g - 4096; ncols = 8; nvalid = 8; }
            else if (g < 6400)  { src = kw;   dst = kwsw; frag = g - 4352; }
            else if (g < 8448)  { src = qw;   dst = qwsw; frag = g - 6400; }
            else                { src = vw;   dst = vwsw; frag = g - 8448; }
            const int s = (frag >> 6) & 3;
            const int l = frag & 63;
            const int n = ((frag >> 8) << 4) + (l & 15);
            Pk8 pk;
            #pragma unroll
            for (int j = 0; j < 8; ++j) {
                const int k = s * 32 + (l >> 4) * 8 + j;
                const float v = (n < nvalid) ? src[k * ncols + n] : 0.f;
                pk.u[j] = f2bf(v);
            }
            *(uint4*)(dst + (size_t)frag * 8) = pk.v;
            return;
        }
        // ---- layer-1 A-frags (W1^T, natural order, bias-folded, hi/lo) -----
        const int g2  = g - 10496;          // [0, 1536)
        const int mlp = g2 >> 9;            // 0:ea 1:ek 2:ev
        const int q   = g2 & 511;
        const int mt  = q >> 6;             // output-dim tile
        const int l   = q & 63;             // lane
        const int mi  = l & 15;             // within-tile output row (A row)
        const int gk  = l >> 4;             // k-group
        const float* w1 = (mlp == 0) ? eaw1 : (mlp == 1) ? ekw1 : evw1;
        const float* b1 = (mlp == 0) ? eab1 : (mlp == 1) ? ekb1 : evb1;
        const int neuron = mt * 16 + mi;    // NATURAL order
        Pk8 pk;
        #pragma unroll
        for (int j = 0; j < 8; ++j) {
            const int kf = gk * 8 + j;
            float v = 0.f; bool lo = false;
            if (kf < FE)                            v = w1[kf * D + neuron];
            else if (kf >= 8  && kf < 8  + FE)      v = w1[(kf - 8) * D + neuron];
            else if (kf >= 16 && kf < 16 + FE)    { v = w1[(kf - 16) * D + neuron]; lo = true; }
            else if (kf == 24)                      v = b1[neuron];
            else if (kf == 25)                    { v = b1[neuron]; lo = true; }
            const ushort_t hi = f2bf(v);
            pk.u[j] = lo ? f2bf(v - bf2f(hi)) : hi;
        }
        *(uint4*)(w1fg + (size_t)g2 * 8) = pk.v;
        return;
    }
    // ---------------- histogram ------------------------------------------
    const int e = (blockIdx.x - 47) * 256 + t;
    if (e < E) atomicAdd(&cnt[bidx[e] * LSEQ + hidx[e]], 1);
}

// ---------------------------------------------------------------------------
// Exclusive scan of the 16384-bin histogram (single block, ~5 µs).
// ---------------------------------------------------------------------------
__global__ __launch_bounds__(1024) void scan16k(
    const int* __restrict__ cnt, int* __restrict__ base)
{
    __shared__ int part[1024];
    const int t = threadIdx.x;
    int v[16], ex[16], s = 0;
    #pragma unroll
    for (int i = 0; i < 16; ++i) v[i] = cnt[t * 16 + i];
    #pragma unroll
    for (int i = 0; i < 16; ++i) { ex[i] = s; s += v[i]; }
    part[t] = s;
    __syncthreads();
    for (int off = 1; off < 1024; off <<= 1) {
        const int x = (t >= off) ? part[t - off] : 0;
        __syncthreads();
        part[t] += x;
        __syncthreads();
    }
    const int boff = (t > 0) ? part[t - 1] : 0;
    #pragma unroll
    for (int i = 0; i < 16; ++i) base[t * 16 + i] = boff + ex[i];
    if (t == 1023) base[NNODE] = boff + s;
}

// ---------------------------------------------------------------------------
// mid_kernel: two independent jobs overlapped in one dispatch:
//   blocks [0, 3*nqm)  : MFMA qkv GEMMs, 64 rows/block, bf16 out.
//   blocks [3*nqm, +)  : scatter_rec — sorted slot p per edge, packed 32 B
//                        record rec[p] = {ef[5], head, tail, pad}.
// ---------------------------------------------------------------------------
__global__ __launch_bounds__(256) void mid_kernel(
    const float* __restrict__ key, const float* __restrict__ value,
    const float* __restrict__ query,
    const float* __restrict__ key_b, const float* __restrict__ value_b,
    const float* __restrict__ query_b,
    const ushort_t* __restrict__ kwsw, const ushort_t* __restrict__ vwsw,
    const ushort_t* __restrict__ qwsw,
    ushort_t* __restrict__ k16, ushort_t* __restrict__ v16, ushort_t* __restrict__ q16,
    const int* __restrict__ bidx, const int* __restrict__ hidx, const int* __restrict__ tidx,
    const float* __restrict__ edge_feats,
    const int* __restrict__ base, int* __restrict__ cnt, float* __restrict__ rec,
    int nqm, int E)
{
    const int t  = threadIdx.x;
    const int nq = 3 * nqm;
    if ((int)blockIdx.x < nq) {
        const int which = blockIdx.x / nqm;
        const int blk   = blockIdx.x % nqm;
        const float* X     = (which == 0) ? key   : (which == 1) ? value   : query;
        const float* bias  = (which == 0) ? key_b : (which == 1) ? value_b : query_b;
        const ushort_t* Ww = (which == 0) ? kwsw  : (which == 1) ? vwsw    : qwsw;
        ushort_t* Y        = (which == 0) ? k16   : (which == 1) ? v16     : q16;

        const int mt    = t >> 6;
        const int l     = t & 63;
        const int rbase = blk * 64 + mt * 16;
        const int colb  = l & 15;
        const int row0  = (l >> 4) * 4;
        const int arow  = rbase + colb;        // A row for this lane (m = l&15)
        const int koff  = (l >> 4) * 8;        // k-offset within 32-chunk

        bf16x8 afr[4];
        #pragma unroll
        for (int s = 0; s < 4; ++s) {
            const float4 x0 = *(const float4*)&X[(size_t)arow * D + s * 32 + koff];
            const float4 x1 = *(const float4*)&X[(size_t)arow * D + s * 32 + koff + 4];
            Pk8 p8;
            p8.u[0] = f2bf(x0.x); p8.u[1] = f2bf(x0.y);
            p8.u[2] = f2bf(x0.z); p8.u[3] = f2bf(x0.w);
            p8.u[4] = f2bf(x1.x); p8.u[5] = f2bf(x1.y);
            p8.u[6] = f2bf(x1.z); p8.u[7] = f2bf(x1.w);
            afr[s] = __builtin_bit_cast(bf16x8, p8.v);
        }
        #pragma unroll
        for (int nt = 0; nt < 8; ++nt) {
            f32x4 acc = {0.f, 0.f, 0.f, 0.f};
            #pragma unroll
            for (int s = 0; s < 4; ++s) {
                const bf16x8 bfr = *(const bf16x8*)(Ww + (size_t)((nt * 4 + s) * 64 + l) * 8);
                acc = __builtin_amdgcn_mfma_f32_16x16x32_bf16(afr[s], bfr, acc, 0, 0, 0);
            }
            const int col = nt * 16 + colb;
            const float b = bias[col];
            #pragma unroll
            for (int r = 0; r < 4; ++r)
                Y[(size_t)(rbase + row0 + r) * D + col] = f2bf(acc[r] + b);
        }
        return;
    }

    // ---------------- scatter_rec ----------------------------------------
    const int e = (blockIdx.x - nq) * 256 + t;
    if (e >= E) return;
    const int bb = bidx[e];
    const int nh = bb * LSEQ + hidx[e];
    const int nt = bb * LSEQ + tidx[e];
    const int slot = atomicSub(&cnt[nh], 1) - 1;
    const int p = base[nh] + slot;
    float ef[FE];
    #pragma unroll
    for (int f = 0; f < FE; ++f) ef[f] = edge_feats[(size_t)e * FE + f];
    *(float4*)&rec[(size_t)p * 8]     = float4{ef[0], ef[1], ef[2], ef[3]};
    *(float4*)&rec[(size_t)p * 8 + 4] = float4{ef[4], i2f(nh), i2f(nt), 0.f};
}

// ---------------------------------------------------------------------------
// Fused edge kernel over SORTED positions. Layer-1 frags from GLOBAL w1fg
// (LDS-staging of w1f failed 3/3 at ~1e-2 absmax — R1/R4/R5, mechanism
// unexplained; global path passed 3/3 — do NOT re-stage w1f in LDS).
// R17: SINGLE-PASS layer-1 (R2's exact math, which PASSED numerically) at
// the (256,3)=170-reg budget. R6's two-pass + unroll-2 fixed the spill but
// serialized the w1fg loads: 24 exposed ~100-200cyc waits/wave at 3
// waves/SIMD = latency-bound (VALUBusy 52%, HBM 11%). Single-pass holds
// f32x4 acc[8] (32 regs) across the LN reduce: -12 MFMA, -24 global loads,
// load-wait points per MLP drop 8 -> ~2. Demand ~140-155 < 170 -> no spill
// (R2's spill was at the (256,4)=128 budget). acc loop FULLY unrolled
// (static indices per rule #20). Tripwire: WRITE_SIZE must stay ~74 MB.
// ---------------------------------------------------------------------------
__global__ __launch_bounds__(256, 3) void edge_kernel(
    const float* __restrict__ rec,
    const ushort_t* __restrict__ w1fg,
    const float* __restrict__ ea_g,  const float* __restrict__ ea_be, const float* __restrict__ ea_b2,
    const float* __restrict__ ek_g,  const float* __restrict__ ek_be, const float* __restrict__ ek_b2,
    const float* __restrict__ ev_g,  const float* __restrict__ ev_be, const float* __restrict__ ev_b2,
    const ushort_t* __restrict__ easw, const ushort_t* __restrict__ eksw, const ushort_t* __restrict__ evsw,
    const ushort_t* __restrict__ k16, const ushort_t* __restrict__ q16, const ushort_t* __restrict__ v16,
    float* __restrict__ ex_ws, ushort_t* __restrict__ vs_ws)
{
    __shared__ ushort_t hn[4][16][136];     // 17 KB wave-local h_n round-trip
    __shared__ float pg[3][D], pbe[3][D];
    __shared__ float pb2k[D], pb2v[D], pb2a[NHEAD];
    __shared__ float ef_s[EPB][FE];
    __shared__ int   eh_s[EPB], et_s[EPB];

    const int t   = threadIdx.x;
    const int e0g = blockIdx.x * EPB;   // sorted-position base

    if (t < D) {
        pg [0][t] = ea_g [t]; pg [1][t] = ek_g [t]; pg [2][t] = ev_g [t];
        pbe[0][t] = ea_be[t]; pbe[1][t] = ek_be[t]; pbe[2][t] = ev_be[t];
        pb2k[t] = ek_b2[t];   pb2v[t] = ev_b2[t];
        if (t < NHEAD) pb2a[t] = ea_b2[t];
    }
    if (t < 128) {
        const int pl = t >> 1, half = t & 1;
        const float4 v = *(const float4*)&rec[((size_t)e0g + pl) * 8 + half * 4];
        if (half == 0) {
            ef_s[pl][0] = v.x; ef_s[pl][1] = v.y; ef_s[pl][2] = v.z; ef_s[pl][3] = v.w;
        } else {
            ef_s[pl][4] = v.x; eh_s[pl] = f2i(v.y); et_s[pl] = f2i(v.z);
        }
    }
    __syncthreads();     // the only barrier

    const int mt   = t >> 6;        // wave id == m-tile (16 edges per wave)
    const int l    = t & 63;        // lane
    const int h4   = l >> 4;        // k-group / h-group
    const int row0 = h4 * 4;        // consumer: accumulator row base
    const int colb = l & 15;        // consumer: column within n-tile
    const int bsrc = (l & 48);      // row-group base for ea broadcasts

    // ---- shared layer-1 B operand: X^T frag (edge = l&15), hi/lo + bias ----
    bf16x8 xfr;
    {
        const float* e = ef_s[mt * 16 + colb];
        Pk8 xf;
        if (h4 == 3) {
            const ushort_t one = f2bf(1.f);
            xf.u[0] = one; xf.u[1] = one;
            #pragma unroll
            for (int j = 2; j < 8; ++j) xf.u[j] = 0;
        } else {
            #pragma unroll
            for (int f = 0; f < FE; ++f) {
                const float v = e[f];
                const ushort_t hi = f2bf(v);
                xf.u[f] = (h4 == 1) ? f2bf(v - bf2f(hi)) : hi;
            }
            xf.u[5] = 0; xf.u[6] = 0; xf.u[7] = 0;
        }
        xfr = __builtin_bit_cast(bf16x8, xf.v);
    }

    ushort_t* hnrow = &hn[mt][colb][0];     // this lane's edge row (wave-local)

    // layer-1 via single-pass MFMA; h_n lands in afr[] via the LDS round-trip.
    auto first_layer = [&](int m, bf16x8 afr[4]) {
        const f32x4 zero = {0.f, 0.f, 0.f, 0.f};
        f32x4 acc[8];
        float s1 = 0.f, s2 = 0.f;
        #pragma unroll
        for (int mtile = 0; mtile < 8; ++mtile) {
            const bf16x8 aw = *(const bf16x8*)(w1fg + (size_t)((m * 8 + mtile) * 64 + l) * 8);
            acc[mtile] = __builtin_amdgcn_mfma_f32_16x16x32_bf16(aw, xfr, zero, 0, 0, 0);
            #pragma unroll
            for (int r = 0; r < 4; ++r) {
                const float v = fmaxf(acc[mtile][r], 0.f);
                acc[mtile][r] = v;
                s1 += v; s2 += v * v;
            }
        }
        s1 += __shfl_xor(s1, 16); s1 += __shfl_xor(s1, 32);
        s2 += __shfl_xor(s2, 16); s2 += __shfl_xor(s2, 32);
        const float mu = s1 * (1.f / 128.f);
        const float rs = rsqrtf(s2 * (1.f / 128.f) - mu * mu + EPS_LN);
        // normalize from registers, store to wave-local LDS (D-layout:
        // lane holds rows 4*h4+r of m-tile mtile for edge colb; natural
        // neuron = mtile*16 + 4*h4 + r).
        #pragma unroll
        for (int mtile = 0; mtile < 8; ++mtile) {
            const int n0 = mtile * 16 + 4 * h4;
            const float4 g4 = *(const float4*)&pg[m][n0];
            const float4 b4 = *(const float4*)&pbe[m][n0];
            uint2 w;
            w.x = (unsigned)f2bf(fmaf((acc[mtile][0] - mu) * rs, g4.x, b4.x))
                | ((unsigned)f2bf(fmaf((acc[mtile][1] - mu) * rs, g4.y, b4.y)) << 16);
            w.y = (unsigned)f2bf(fmaf((acc[mtile][2] - mu) * rs, g4.z, b4.z))
                | ((unsigned)f2bf(fmaf((acc[mtile][3] - mu) * rs, g4.w, b4.w)) << 16);
            *(uint2*)&hnrow[n0] = w;
        }
        // pinned A-pattern read: elem j of frag s = h_n[edge l&15][32s+8h4+j]
        #pragma unroll
        for (int s = 0; s < 4; ++s)
            afr[s] = *(const bf16x8*)&hnrow[32 * s + 8 * h4];
    };

    bf16x8 afr[4];

    // ================= MLP 0: ea (attention bias, cols padded 8->16) ========
    float eaacc[4];
    first_layer(0, afr);
    {
        f32x4 acc = {0.f, 0.f, 0.f, 0.f};
        #pragma unroll
        for (int s = 0; s < 4; ++s) {
            const bf16x8 bfr = *(const bf16x8*)(easw + (size_t)(s * 64 + l) * 8);
            acc = __builtin_amdgcn_mfma_f32_16x16x32_bf16(afr[s], bfr, acc, 0, 0, 0);
        }
        #pragma unroll
        for (int r = 0; r < 4; ++r) eaacc[r] = acc[r];   // raw; bias added later
    }

    // ================= MLP 1: ek -> scores -> exp -> ex_ws ==================
    first_layer(1, afr);
    #pragma unroll
    for (int nt = 0; nt < NHEAD; ++nt) {
        f32x4 acc = {0.f, 0.f, 0.f, 0.f};
        #pragma unroll
        for (int s = 0; s < 4; ++s) {
            const bf16x8 bfr = *(const bf16x8*)(eksw + (size_t)((nt * 4 + s) * 64 + l) * 8);
            acc = __builtin_amdgcn_mfma_f32_16x16x32_bf16(afr[s], bfr, acc, 0, 0, 0);
        }
        const int col = nt * 16 + colb;
        const float b2 = pb2k[col];
        const float ba = pb2a[nt];
        float pr[4];
        #pragma unroll
        for (int r = 0; r < 4; ++r) {
            const int tnr  = et_s[mt*16 + row0 + r];
            const int hnr  = eh_s[mt*16 + row0 + r];
            pr[r] = (acc[r] + b2 + bf2f(k16[(size_t)tnr * D + col]))
                    * bf2f(q16[(size_t)hnr * D + col]);
        }
        #pragma unroll
        for (int m = 1; m < 16; m <<= 1) {
            #pragma unroll
            for (int r = 0; r < 4; ++r) pr[r] += __shfl_xor(pr[r], m);
        }
        #pragma unroll
        for (int r = 0; r < 4; ++r) {
            // segment-max skipped: |score| small, exp cannot overflow.
            const float ea = __shfl(eaacc[r], bsrc | nt);
            const float ex = __expf(pr[r] + ea + ba);
            if (colb == nt)
                ex_ws[(size_t)(e0g + mt*16 + row0 + r) * NHEAD + nt] = ex;
        }
    }

    // ================= MLP 2: ev -> raw vs (bf16) ===========================
    first_layer(2, afr);
    #pragma unroll
    for (int nt = 0; nt < NHEAD; ++nt) {
        f32x4 acc = {0.f, 0.f, 0.f, 0.f};
        #pragma unroll
        for (int s = 0; s < 4; ++s) {
            const bf16x8 bfr = *(const bf16x8*)(evsw + (size_t)((nt * 4 + s) * 64 + l) * 8);
            acc = __builtin_amdgcn_mfma_f32_16x16x32_bf16(afr[s], bfr, acc, 0, 0, 0);
        }
        const int col = nt * 16 + colb;
        const float b2 = pb2v[col];
        #pragma unroll
        for (int r = 0; r < 4; ++r) {
            const int tnr = et_s[mt*16 + row0 + r];
            const float vs = acc[r] + b2 + bf2f(v16[(size_t)tnr * D + col]);
            vs_ws[(size_t)(e0g + mt*16 + row0 + r) * D + col] = f2bf(vs);
        }
    }
}

// ---------------------------------------------------------------------------
// agg_out: 512 threads, 16 nodes per block, 4 row-groups (4 nodes each).
// Phase 1: stream each node's contiguous sorted segment of (ex, vs) -> LDS y.
// Phase 2: project y @ W + b (each row-group does 4 output rows).
// Plain bounds: no waves/EU contract (R9/R10: never squeeze the allocator).
// ---------------------------------------------------------------------------
__global__ __launch_bounds__(512) void agg_out(
    const int* __restrict__ base,
    const float* __restrict__ ex_ws, const ushort_t* __restrict__ vs_ws,
    const float* __restrict__ W, const float* __restrict__ bias,
    float* __restrict__ out)
{
    __shared__ float xs[D][20];
    const int t  = threadIdx.x;
    const int rg = t >> 7;          // 0..3: node/row group
    const int j  = t & 127;
    const int h  = j >> 4;
    const int n0 = blockIdx.x * 16;

    // ---- phase 1: per-node segmented reduction (contiguous, no indices) ----
    #pragma unroll
    for (int ni = 0; ni < 4; ++ni) {
        const int n  = n0 + rg * 4 + ni;
        const int s0 = base[n], s1 = base[n + 1];
        float acc = 0.f, den = 0.f;
        int p = s0;
        for (; p + 4 <= s1; p += 4) {
            float ex4[4], vs4[4];
            #pragma unroll
            for (int r = 0; r < 4; ++r) {
                ex4[r] = ex_ws[(size_t)(p + r) * NHEAD + h];
                vs4[r] = bf2f(vs_ws[(size_t)(p + r) * D + j]);
            }
            #pragma unroll
            for (int r = 0; r < 4; ++r) {
                den += ex4[r];
                acc = fmaf(ex4[r], vs4[r], acc);
            }
        }
        for (; p < s1; ++p) {
            const float ex = ex_ws[(size_t)p * NHEAD + h];
            den += ex;
            acc = fmaf(ex, bf2f(vs_ws[(size_t)p * D + j]), acc);
        }
        xs[j][rg * 4 + ni] = acc / (den + EPS_SM);
    }
    __syncthreads();

    // ---- phase 2: out projection; row-group rg does rows rg*4..rg*4+4 ------
    float acc[4];
    const float b = bias[j];
    #pragma unroll
    for (int r = 0; r < 4; ++r) acc[r] = b;
    #pragma unroll 4
    for (int i = 0; i < D; ++i) {
        const float w = W[i * D + j];
        const float4 y4 = *(const float4*)&xs[i][rg * 4];
        acc[0] = fmaf(y4.x, w, acc[0]); acc[1] = fmaf(y4.y, w, acc[1]);
        acc[2] = fmaf(y4.z, w, acc[2]); acc[3] = fmaf(y4.w, w, acc[3]);
    }
    #pragma unroll
    for (int r = 0; r < 4; ++r)
        out[(size_t)(n0 + rg * 4 + r) * D + j] = acc[r];
}

// ---------------------------------------------------------------------------
extern "C" void kernel_launch(void* const* d_in, const int* in_sizes, int n_in,
                              void* d_out, int out_size, void* d_ws, size_t ws_size,
                              hipStream_t stream)
{
    const float* key        = (const float*)d_in[0];
    const float* value      = (const float*)d_in[1];
    const float* query      = (const float*)d_in[2];
    const float* edge_feats = (const float*)d_in[3];
    const int*   bidx       = (const int*)d_in[5];
    const int*   hidx       = (const int*)d_in[6];
    const int*   tidx       = (const int*)d_in[7];
    const float* key_w   = (const float*)d_in[8];  const float* key_b   = (const float*)d_in[9];
    const float* query_w = (const float*)d_in[10]; const float* query_b = (const float*)d_in[11];
    const float* value_w = (const float*)d_in[12]; const float* value_b = (const float*)d_in[13];
    const float* proj_w  = (const float*)d_in[14]; const float* proj_b  = (const float*)d_in[15];

    const int N = in_sizes[0] / D;   // 16384 nodes
    const int E = in_sizes[5];       // 262144 edges

    char* ws = (char*)d_ws;
    ushort_t* k16   = (ushort_t*)ws; ws += (size_t)N * D * 2;
    ushort_t* q16   = (ushort_t*)ws; ws += (size_t)N * D * 2;
    ushort_t* v16   = (ushort_t*)ws; ws += (size_t)N * D * 2;
    float* ex_ws    = (float*)ws;    ws += (size_t)E * NHEAD * 4;
    ushort_t* vs_ws = (ushort_t*)ws; ws += (size_t)E * D * 2;
    float* rec      = (float*)ws;    ws += (size_t)E * 8 * 4;
    ushort_t* eksw  = (ushort_t*)ws; ws += (size_t)2048 * 8 * 2;
    ushort_t* evsw  = (ushort_t*)ws; ws += (size_t)2048 * 8 * 2;
    ushort_t* easw  = (ushort_t*)ws; ws += (size_t)256 * 8 * 2;
    ushort_t* kwsw  = (ushort_t*)ws; ws += (size_t)2048 * 8 * 2;
    ushort_t* qwsw  = (ushort_t*)ws; ws += (size_t)2048 * 8 * 2;
    ushort_t* vwsw  = (ushort_t*)ws; ws += (size_t)2048 * 8 * 2;
    ushort_t* w1fg  = (ushort_t*)ws; ws += (size_t)1536 * 8 * 2;
    int* base = (int*)ws;  ws += (size_t)(N + 1) * 4;
    int* cnt  = (int*)ws;  ws += (size_t)N * 4;

    const int nqm   = N / 64;             // MFMA-qkv blocks per matrix (256)
    const int nhist = (E + 255) / 256;    // 1024

    hipMemsetAsync(cnt, 0, (size_t)N * 4, stream);

    pre_kernel<<<47 + nhist, 256, 0, stream>>>(
        (const float*)d_in[26], (const float*)d_in[32], (const float*)d_in[20],
        key_w, query_w, value_w,
        (const float*)d_in[16], (const float*)d_in[17],
        (const float*)d_in[22], (const float*)d_in[23],
        (const float*)d_in[28], (const float*)d_in[29],
        eksw, evsw, easw, kwsw, qwsw, vwsw, w1fg,
        bidx, hidx, cnt, E);

    scan16k<<<1, 1024, 0, stream>>>(cnt, base);

    mid_kernel<<<3 * nqm + nhist, 256, 0, stream>>>(
        key, value, query,
        key_b, value_b, query_b,
        kwsw, vwsw, qwsw,
        k16, v16, q16,
        bidx, hidx, tidx, edge_feats,
        base, cnt, rec, nqm, E);

    edge_kernel<<<E / EPB, 256, 0, stream>>>(
        rec, w1fg,
        (const float*)d_in[18], (const float*)d_in[19], (const float*)d_in[21],
        (const float*)d_in[24], (const float*)d_in[25], (const float*)d_in[27],
        (const float*)d_in[30], (const float*)d_in[31], (const float*)d_in[33],
        easw, eksw, evsw,
        k16, q16, v16,
        ex_ws, vs_ws);

    agg_out<<<N / 16, 512, 0, stream>>>(base, ex_ws, vs_ws, proj_w, proj_b, (float*)d_out);
}